// Round 6
// baseline (517.967 us; speedup 1.0000x reference)
//
#include <hip/hip_runtime.h>
#include <math.h>

#define BATCH 2
#define SEQ   2048
#define DIM   1024
#define NST   16
#define DTR   64
#define NCH   16                    // time chunks for the scan
#define CHUNK (SEQ / NCH)           // 128 steps per chunk
#define LANES (BATCH * DIM * NST)   // 32768 scan lanes
#define KSL   8                     // split-K slices for x_proj

typedef _Float16 f16x8 __attribute__((ext_vector_type(8)));
typedef float f32x4 __attribute__((ext_vector_type(4)));

__device__ __forceinline__ float softplus_f(float v) {
  return fmaxf(v, 0.f) + log1pf(expf(-fabsf(v)));
}
__device__ __forceinline__ float silu_f(float v) {
  return v / (1.f + expf(-v));
}

__device__ __forceinline__ void gl_lds16(const _Float16* g, _Float16* l) {
  __builtin_amdgcn_global_load_lds(
      (const __attribute__((address_space(1))) void*)g,
      (__attribute__((address_space(3))) void*)l, 16, 0, 0);
}

#define FMA_ROW(i, av)                                        \
  acc[i][0] = fmaf(av, b.x, acc[i][0]);                       \
  acc[i][1] = fmaf(av, b.y, acc[i][1]);                       \
  acc[i][2] = fmaf(av, b.z, acc[i][2]);                       \
  acc[i][3] = fmaf(av, b.w, acc[i][3]);

// ---------------- split fp32 -> hi/lo f16 planes ----------------
__global__ __launch_bounds__(256) void k_cvt(const float* __restrict__ in,
                                             _Float16* __restrict__ hi,
                                             _Float16* __restrict__ lo,
                                             int n) {
  const int i = (blockIdx.x * 256 + threadIdx.x) * 8;
  if (i >= n) return;
  const float4 a = *(const float4*)(in + i);
  const float4 b = *(const float4*)(in + i + 4);
  const float v[8] = {a.x, a.y, a.z, a.w, b.x, b.y, b.z, b.w};
  f16x8 h, l;
#pragma unroll
  for (int j = 0; j < 8; ++j) {
    const _Float16 hh = (_Float16)v[j];
    h[j] = hh;
    l[j] = (_Float16)(v[j] - (float)hh);
  }
  *(f16x8*)(hi + i) = h;
  *(f16x8*)(lo + i) = l;
}

// ---------------- f16x3 NT GEMM: D[m][n] = sum_k A[m,k]*B[n,k], K=LD=1024 ----
template <int EPI>
__global__ __launch_bounds__(256) void kgemm_f16x3(
    const _Float16* __restrict__ Ah, const _Float16* __restrict__ Al,
    const _Float16* __restrict__ Bh, const _Float16* __restrict__ Bl,
    float* __restrict__ out0, float* __restrict__ out1) {
  __shared__ _Float16 sm[16384];  // 32 KB: Ah|Al|Bh|Bl tiles, 128x32 packed
  _Float16* Ash = sm;
  _Float16* Asl = sm + 4096;
  _Float16* Bsh = sm + 8192;
  _Float16* Bsl = sm + 12288;

  const int tid = threadIdx.x;
  const int wid = tid >> 6, lane = tid & 63;
  const int wm = wid >> 1, wn = wid & 1;
  const int m0 = blockIdx.y * 128;
  const int n0 = blockIdx.x * 128;

  const int r0 = wid * 32;
  const int srow = lane >> 2;
  const int skq = (lane & 3) * 8;
  const _Float16* gAh = Ah + (size_t)(m0 + r0 + srow) * 1024 + skq;
  const _Float16* gAl = Al + (size_t)(m0 + r0 + srow) * 1024 + skq;
  const _Float16* gBh = Bh + (size_t)(n0 + r0 + srow) * 1024 + skq;
  const _Float16* gBl = Bl + (size_t)(n0 + r0 + srow) * 1024 + skq;
  _Float16* lAh = Ash + r0 * 32;
  _Float16* lAl = Asl + r0 * 32;
  _Float16* lBh = Bsh + r0 * 32;
  _Float16* lBl = Bsl + r0 * 32;

  const int fr = lane & 15;
  const int fk = (lane >> 4) * 8;

  f32x4 acc[4][4];
#pragma unroll
  for (int i = 0; i < 4; ++i)
#pragma unroll
    for (int j = 0; j < 4; ++j) acc[i][j] = (f32x4)(0.f);

  for (int k0 = 0; k0 < 1024; k0 += 32) {
    __syncthreads();
    gl_lds16(gAh + k0, lAh);
    gl_lds16(gAh + k0 + 16 * 1024, lAh + 512);
    gl_lds16(gAl + k0, lAl);
    gl_lds16(gAl + k0 + 16 * 1024, lAl + 512);
    gl_lds16(gBh + k0, lBh);
    gl_lds16(gBh + k0 + 16 * 1024, lBh + 512);
    gl_lds16(gBl + k0, lBl);
    gl_lds16(gBl + k0 + 16 * 1024, lBl + 512);
    __syncthreads();

    f16x8 ah[4], alo[4], bh[4], blo[4];
#pragma unroll
    for (int i = 0; i < 4; ++i) {
      const int ao = (wm * 64 + i * 16 + fr) * 32 + fk;
      const int bo = (wn * 64 + i * 16 + fr) * 32 + fk;
      ah[i]  = *(const f16x8*)(Ash + ao);
      alo[i] = *(const f16x8*)(Asl + ao);
      bh[i]  = *(const f16x8*)(Bsh + bo);
      blo[i] = *(const f16x8*)(Bsl + bo);
    }
#pragma unroll
    for (int i = 0; i < 4; ++i)
#pragma unroll
      for (int j = 0; j < 4; ++j) {
        acc[i][j] = __builtin_amdgcn_mfma_f32_16x16x32_f16(ah[i], bh[j],
                                                           acc[i][j], 0, 0, 0);
        acc[i][j] = __builtin_amdgcn_mfma_f32_16x16x32_f16(ah[i], blo[j],
                                                           acc[i][j], 0, 0, 0);
        acc[i][j] = __builtin_amdgcn_mfma_f32_16x16x32_f16(alo[i], bh[j],
                                                           acc[i][j], 0, 0, 0);
      }
  }

  const int lr4 = (lane >> 4) * 4, lc = lane & 15;
#pragma unroll
  for (int i = 0; i < 4; ++i) {
#pragma unroll
    for (int j = 0; j < 4; ++j) {
      const int ar = m0 + wm * 64 + i * 16 + lr4;
      const int bc = n0 + wn * 64 + j * 16 + lc;
#pragma unroll
      for (int r = 0; r < 4; ++r) {
        const float v = acc[i][j][r];
        if (EPI == 0) {
          out0[(size_t)(ar + r) * 1024 + bc] = v;
        } else {
          const int bb = bc >> 11, tt = bc & 2047;
          if (ar < 1024) {
            out0[((size_t)bb * 1024 + ar + r) * 2048 + tt] = v;
          } else {
            out1[((size_t)bb * 1024 + (ar + r - 1024)) * 2048 + tt] = v;
          }
        }
      }
    }
  }
}

// ---------------- conv: depthwise k=3, pad=1, along t ----------------
__global__ __launch_bounds__(256) void k_conv(
    const float* __restrict__ xcraw, const float* __restrict__ cw,
    const float* __restrict__ cb, float* __restrict__ xc) {
  const int idx = blockIdx.x * 256 + threadIdx.x;
  const int t0 = (idx & (SEQ / 4 - 1)) * 4;
  const int r = idx >> 9;  // b*DIM + d
  const int d = r & (DIM - 1);
  const float w0 = cw[d * 3 + 0], w1 = cw[d * 3 + 1], w2 = cw[d * 3 + 2];
  const float bias = cb[d];
  const float* in = xcraw + (size_t)r * SEQ;
  float o[4];
#pragma unroll
  for (int j = 0; j < 4; ++j) {
    const int t = t0 + j;
    const float xm = (t > 0) ? in[t - 1] : 0.f;
    const float x0 = in[t];
    const float xp = (t < SEQ - 1) ? in[t + 1] : 0.f;
    o[j] = fmaf(w0, xm, fmaf(w1, x0, fmaf(w2, xp, bias)));
  }
  *(float4*)(xc + (size_t)r * SEQ + t0) = make_float4(o[0], o[1], o[2], o[3]);
}

// ---------------- K2: x_proj split-K GEMM ----------------
__global__ __launch_bounds__(256) void k2_xproj_sk(
    const float* __restrict__ xc, const float* __restrict__ wp,
    float* __restrict__ part) {
  __shared__ float As[16][100];   // [kk][j], +4 pad
  __shared__ float Bs[16][132];   // [kk][t], +4 pad
  const int tid = threadIdx.x;
  const int tile = blockIdx.x;            // 0..31
  const int ks = blockIdx.y;              // 0..KSL-1
  const int b = tile >> 4;
  const int t0 = (tile & 15) * 128;
  const int kbase = ks * (DIM / KSL);     // 128-wide K slice
  const int tx = tid & 15, ty = tid >> 4;
  float acc[6][8] = {{0.f}};
  for (int k = 0; k < DIM / KSL; k += 16) {
    float a_reg[6];
#pragma unroll
    for (int i = 0; i < 6; ++i) {
      const int ii = tid + 256 * i;
      a_reg[i] = wp[(size_t)(ii >> 4) * DIM + kbase + k + (ii & 15)];
    }
    float4 b_reg[2];
#pragma unroll
    for (int r = 0; r < 2; ++r) {
      const int id2 = tid + 256 * r;
      const int krow = id2 >> 5, t4 = (id2 & 31) * 4;
      b_reg[r] = *(const float4*)(xc + ((size_t)b * DIM + kbase + k + krow) *
                                           SEQ + t0 + t4);
    }
    __syncthreads();
#pragma unroll
    for (int i = 0; i < 6; ++i) {
      const int ii = tid + 256 * i;
      As[ii & 15][ii >> 4] = a_reg[i];
    }
#pragma unroll
    for (int r = 0; r < 2; ++r) {
      const int id2 = tid + 256 * r;
      const int krow = id2 >> 5, t4 = (id2 & 31) * 4;
      *(float4*)&Bs[krow][t4] = b_reg[r];
    }
    __syncthreads();
#pragma unroll
    for (int kk = 0; kk < 16; ++kk) {
      const float4 bA = *(const float4*)&Bs[kk][tx * 4];
      const float4 bB = *(const float4*)&Bs[kk][64 + tx * 4];
#pragma unroll
      for (int i = 0; i < 6; ++i) {
        const float a = As[kk][ty + 16 * i];
        acc[i][0] = fmaf(a, bA.x, acc[i][0]);
        acc[i][1] = fmaf(a, bA.y, acc[i][1]);
        acc[i][2] = fmaf(a, bA.z, acc[i][2]);
        acc[i][3] = fmaf(a, bA.w, acc[i][3]);
        acc[i][4] = fmaf(a, bB.x, acc[i][4]);
        acc[i][5] = fmaf(a, bB.y, acc[i][5]);
        acc[i][6] = fmaf(a, bB.z, acc[i][6]);
        acc[i][7] = fmaf(a, bB.w, acc[i][7]);
      }
    }
    __syncthreads();
  }
#pragma unroll
  for (int i = 0; i < 6; ++i) {
    const int j = ty + 16 * i;
    const size_t o = ((size_t)(ks * BATCH + b) * 96 + j) * SEQ + t0;
    *(float4*)(part + o + tx * 4) =
        make_float4(acc[i][0], acc[i][1], acc[i][2], acc[i][3]);
    *(float4*)(part + o + 64 + tx * 4) =
        make_float4(acc[i][4], acc[i][5], acc[i][6], acc[i][7]);
  }
}

// ---------------- reduce split-K partials -> xdbl ----------------
__global__ __launch_bounds__(256) void k_red(const float* __restrict__ part,
                                             float* __restrict__ xdbl) {
  const size_t PL = (size_t)BATCH * 96 * SEQ;  // 393216
  const size_t i4 = ((size_t)blockIdx.x * 256 + threadIdx.x) * 4;
  float4 s = *(const float4*)(part + i4);
#pragma unroll
  for (int ks = 1; ks < KSL; ++ks) {
    const float4 v = *(const float4*)(part + ks * PL + i4);
    s.x += v.x; s.y += v.y; s.z += v.z; s.w += v.w;
  }
  *(float4*)(xdbl + i4) = s;
}

// ---------------- K3: dt_proj GEMM + softplus (fp32, small) ----------------
__global__ __launch_bounds__(256) void k3_dtproj(
    const float* __restrict__ xdbl, const float* __restrict__ dtw,
    const float* __restrict__ dtb, float* __restrict__ delta) {
  __shared__ float As[16][68];
  __shared__ float Bs[16][68];
  const int tid = threadIdx.x;
  const int b = blockIdx.z;
  const int d0 = blockIdx.y * 64;
  const int t0 = blockIdx.x * 64;
  const int tx = tid & 15, ty = tid >> 4;
  const int lrow = tid >> 2, lcol = (tid & 3) * 4;
  const int bk = tid >> 4, bt4 = (tid & 15) * 4;
  float acc[4][4] = {{0.f}};
  for (int k = 0; k < DTR; k += 16) {
    const float4 av =
        *(const float4*)(dtw + (size_t)(d0 + lrow) * DTR + k + lcol);
    const float4 bv =
        *(const float4*)(xdbl + ((size_t)b * 96 + k + bk) * SEQ + t0 + bt4);
    __syncthreads();
    As[lcol + 0][lrow] = av.x; As[lcol + 1][lrow] = av.y;
    As[lcol + 2][lrow] = av.z; As[lcol + 3][lrow] = av.w;
    Bs[bk][bt4 + 0] = bv.x; Bs[bk][bt4 + 1] = bv.y;
    Bs[bk][bt4 + 2] = bv.z; Bs[bk][bt4 + 3] = bv.w;
    __syncthreads();
#pragma unroll
    for (int kk = 0; kk < 16; ++kk) {
      const float4 a = *(const float4*)&As[kk][ty * 4];
      const float4 b = *(const float4*)&Bs[kk][tx * 4];
      FMA_ROW(0, a.x) FMA_ROW(1, a.y) FMA_ROW(2, a.z) FMA_ROW(3, a.w)
    }
  }
#pragma unroll
  for (int i = 0; i < 4; ++i) {
    const int d = d0 + ty * 4 + i;
    const float bias = dtb[d];
    float4 v;
    v.x = softplus_f(acc[i][0] + bias);
    v.y = softplus_f(acc[i][1] + bias);
    v.z = softplus_f(acc[i][2] + bias);
    v.w = softplus_f(acc[i][3] + bias);
    *(float4*)(delta + ((size_t)b * DIM + d) * SEQ + t0 + tx * 4) = v;
  }
}

// ---------------- scan pass 1: per-chunk product + local end state ----------
// 256-thread blocks: 16 (b,d) rows per block, one 16-lane group per row.
__global__ __launch_bounds__(256) void k_scan_pass1(
    const float* __restrict__ delta, const float* __restrict__ u,
    const float* __restrict__ xdbl, const float* __restrict__ A_log,
    float* __restrict__ Pbuf, float* __restrict__ Sbuf) {
  const int tid = threadIdx.x;
  const int gid = tid >> 4, n = tid & 15;
  const int bdblk = blockIdx.x & 127;
  const int chunk = blockIdx.x >> 7;
  const int idx = bdblk * 16 + gid;  // b*DIM + d
  const int b = idx >> 10, d = idx & (DIM - 1);
  const float A = -expf(A_log[d * NST + n]);
  const int tc = chunk * CHUNK;
  const float* drow = delta + (size_t)idx * SEQ + tc;
  const float* urow = u + (size_t)idx * SEQ + tc;
  const float* Brow = xdbl + ((size_t)b * 96 + DTR + n) * SEQ + tc;
  float s = 0.f, dsum = 0.f;
  for (int t0 = 0; t0 < CHUNK; t0 += 4) {
    const float4 dl = *(const float4*)(drow + t0);
    const float4 uu = *(const float4*)(urow + t0);
    const float4 Bv = *(const float4*)(Brow + t0);
    const float dls[4] = {dl.x, dl.y, dl.z, dl.w};
    const float us[4] = {uu.x, uu.y, uu.z, uu.w};
    const float Bb[4] = {Bv.x, Bv.y, Bv.z, Bv.w};
#pragma unroll
    for (int j = 0; j < 4; ++j) {
      dsum += dls[j];
      const float dA = __expf(dls[j] * A);
      s = fmaf(dA, s, dls[j] * us[j] * Bb[j]);
    }
  }
  const int gi = chunk * LANES + idx * 16 + n;
  Pbuf[gi] = __expf(dsum * A);
  Sbuf[gi] = s;
}

// ---------------- scan mid ----------------
__global__ __launch_bounds__(64) void k_scan_mid(
    const float* __restrict__ Pbuf, float* __restrict__ Sbuf) {
  const int gl = blockIdx.x * 64 + threadIdx.x;
  float run = 0.f;
#pragma unroll
  for (int c = 0; c < NCH; ++c) {
    const float p = Pbuf[c * LANES + gl];
    const float s = Sbuf[c * LANES + gl];
    Sbuf[c * LANES + gl] = run;
    run = fmaf(p, run, s);
  }
}

// ---------------- scan pass 2: seeded scan; LDS-transpose n-reduction -------
// 256 threads = 4 waves x 4 groups; group = 16 lanes = one (b,d) row.
// Per 16-t window: lane n accumulates c[t]=s*C (+u*D on n==0), writes the
// 16x16 tile to LDS [t][n] (row-rotated per group for bank spread), then
// reads row t=n back as 4x b128 and linearly sums -> y[tw+n]. Wave-local
// LDS (in-order DS pipe) needs no barrier.
__global__ __launch_bounds__(256, 8) void k_scan_pass2(
    const float* __restrict__ delta, const float* __restrict__ u,
    const float* __restrict__ xdbl, const float* __restrict__ A_log,
    const float* __restrict__ Dp, const float* __restrict__ sInit,
    float* __restrict__ y) {
  __shared__ float sc[16][16][20];  // 20 KB: [gid][t][n+pad]
  const int tid = threadIdx.x;
  const int lane = tid & 63;
  const int grp = (lane >> 4) & 3, n = lane & 15;
  const int gid = tid >> 4;          // 0..15
  const int bdblk = blockIdx.x & 127;
  const int chunk = blockIdx.x >> 7;
  const int idx = bdblk * 16 + gid;  // b*DIM + d
  const int b = idx >> 10, d = idx & (DIM - 1);
  const float A = -expf(A_log[d * NST + n]);
  const float Dprm = Dp[d];
  const int tc = chunk * CHUNK;
  const float* drow = delta + (size_t)idx * SEQ + tc;
  const float* urow = u + (size_t)idx * SEQ + tc;
  const float* Brow = xdbl + ((size_t)b * 96 + DTR + n) * SEQ + tc;
  const float* Crow = xdbl + ((size_t)b * 96 + DTR + NST + n) * SEQ + tc;
  float* yrow = y + (size_t)idx * SEQ + tc;
  float s = sInit[chunk * LANES + idx * 16 + n];
  for (int tw = 0; tw < CHUNK; tw += 16) {
    float c[16];
#pragma unroll
    for (int q = 0; q < 4; ++q) {
      const int t0 = tw + q * 4;
      const float4 dl = *(const float4*)(drow + t0);
      const float4 uu = *(const float4*)(urow + t0);
      const float4 Bv = *(const float4*)(Brow + t0);
      const float4 Cv = *(const float4*)(Crow + t0);
      const float dls[4] = {dl.x, dl.y, dl.z, dl.w};
      const float us[4] = {uu.x, uu.y, uu.z, uu.w};
      const float Bb[4] = {Bv.x, Bv.y, Bv.z, Bv.w};
      const float Cc[4] = {Cv.x, Cv.y, Cv.z, Cv.w};
#pragma unroll
      for (int j = 0; j < 4; ++j) {
        const float dA = __expf(dls[j] * A);
        s = fmaf(dA, s, dls[j] * us[j] * Bb[j]);
        float cv = s * Cc[j];
        if (n == 0) cv = fmaf(us[j], Dprm, cv);
        c[q * 4 + j] = cv;
      }
    }
    // scatter column n (row-rotated per group: 2-way banks max)
#pragma unroll
    for (int tt = 0; tt < 16; ++tt) {
      const int t = (tt + 4 * grp) & 15;
      sc[gid][t][n] = c[t];
    }
    // gather row t=n, linear sum
    const float4 r0 = *(const float4*)&sc[gid][n][0];
    const float4 r1 = *(const float4*)&sc[gid][n][4];
    const float4 r2 = *(const float4*)&sc[gid][n][8];
    const float4 r3 = *(const float4*)&sc[gid][n][12];
    float sum = ((r0.x + r0.y) + (r0.z + r0.w)) +
                ((r1.x + r1.y) + (r1.z + r1.w)) +
                ((r2.x + r2.y) + (r2.z + r2.w)) +
                ((r3.x + r3.y) + (r3.z + r3.w));
    yrow[tw + n] = sum;
  }
}

// ---------------- gate + transpose: g=(y*silu(z)) -> gh/gl (n,d) f16 --------
__global__ __launch_bounds__(256) void k_gt(
    const float* __restrict__ y, const float* __restrict__ z,
    _Float16* __restrict__ gh, _Float16* __restrict__ gl) {
  __shared__ _Float16 th[64][68];  // [d_local][t_local]
  __shared__ _Float16 tl[64][68];
  const int ti = threadIdx.x;
  const int t0 = blockIdx.x * 64;
  const int d0 = blockIdx.y * 64;
  const int b = blockIdx.z;
  const int c4 = (ti & 15) * 4;
#pragma unroll
  for (int rr = 0; rr < 4; ++rr) {
    const int dl_ = (ti >> 4) + 16 * rr;
    const size_t base = ((size_t)b * DIM + d0 + dl_) * SEQ + t0 + c4;
    const float4 yv = *(const float4*)(y + base);
    const float4 zv = *(const float4*)(z + base);
    const float gy[4] = {yv.x * silu_f(zv.x), yv.y * silu_f(zv.y),
                         yv.z * silu_f(zv.z), yv.w * silu_f(zv.w)};
#pragma unroll
    for (int k = 0; k < 4; ++k) {
      const _Float16 h = (_Float16)gy[k];
      th[dl_][c4 + k] = h;
      tl[dl_][c4 + k] = (_Float16)(gy[k] - (float)h);
    }
  }
  __syncthreads();
#pragma unroll
  for (int rr = 0; rr < 2; ++rr) {
    const int chunk = ti + 256 * rr;
    const int tloc = chunk >> 3;
    const int dchunk = (chunk & 7) * 8;
    f16x8 hv, lv;
#pragma unroll
    for (int j = 0; j < 8; ++j) {
      hv[j] = th[dchunk + j][tloc];
      lv[j] = tl[dchunk + j][tloc];
    }
    const size_t o = ((size_t)b * SEQ + t0 + tloc) * DIM + d0 + dchunk;
    *(f16x8*)(gh + o) = hv;
    *(f16x8*)(gl + o) = lv;
  }
}

extern "C" void kernel_launch(void* const* d_in, const int* in_sizes, int n_in,
                              void* d_out, int out_size, void* d_ws,
                              size_t ws_size, hipStream_t stream) {
  const float* x          = (const float*)d_in[0];
  const float* in_proj_w  = (const float*)d_in[1];
  const float* conv_w     = (const float*)d_in[2];
  const float* conv_b     = (const float*)d_in[3];
  const float* A_log      = (const float*)d_in[4];
  const float* D_param    = (const float*)d_in[5];
  const float* x_proj_w   = (const float*)d_in[6];
  const float* dt_proj_w  = (const float*)d_in[7];
  const float* dt_proj_b  = (const float*)d_in[8];
  const float* out_proj_w = (const float*)d_in[9];
  float* out = (float*)d_out;
  float* ws = (float*)d_ws;

  const size_t PLANE = (size_t)BATCH * SEQ * DIM;  // 4M floats (16 MB)
  float* xcraw = ws;
  float* delta = ws;
  _Float16* gh = (_Float16*)ws;                    // PLANE f16
  _Float16* gl = (_Float16*)ws + PLANE;            // PLANE f16
  float* xc    = ws + PLANE;      // (b,d,t) post-conv
  float* zbuf  = ws + 2 * PLANE;  // (b,dz,t) channel-major
  _Float16* xh = (_Float16*)(ws + 3 * PLANE);
  _Float16* xl = xh + PLANE;
  float* part  = ws + 3 * PLANE;   // KSL * 393216 = 3.1M floats
  float* ybuf  = ws + 3 * PLANE;
  float* xdbl  = ws + 4 * PLANE;                    // (b,96,t) 393216 floats
  float* scanP = xdbl + (size_t)BATCH * 96 * SEQ;   // 524288 floats
  float* scanS = scanP + (size_t)LANES * NCH;       // 524288 floats
  _Float16* wih = (_Float16*)(ws + 4 * PLANE + 1572864);
  _Float16* wil = wih + (size_t)2 * DIM * DIM;
  _Float16* woh = wil + (size_t)2 * DIM * DIM;
  _Float16* wol = woh + (size_t)DIM * DIM;

  k_cvt<<<dim3(2048), 256, 0, stream>>>(x, xh, xl, BATCH * SEQ * DIM);
  k_cvt<<<dim3(1024), 256, 0, stream>>>(in_proj_w, wih, wil, 2 * DIM * DIM);
  k_cvt<<<dim3(512), 256, 0, stream>>>(out_proj_w, woh, wol, DIM * DIM);

  kgemm_f16x3<1><<<dim3(32, 16), 256, 0, stream>>>(wih, wil, xh, xl,
                                                   xcraw, zbuf);
  k_conv<<<dim3((BATCH * DIM * SEQ / 4) / 256), 256, 0, stream>>>(
      xcraw, conv_w, conv_b, xc);
  k2_xproj_sk<<<dim3(32, KSL), 256, 0, stream>>>(xc, x_proj_w, part);
  k_red<<<dim3(384), 256, 0, stream>>>(part, xdbl);
  k3_dtproj<<<dim3(SEQ / 64, DIM / 64, BATCH), 256, 0, stream>>>(
      xdbl, dt_proj_w, dt_proj_b, delta);
  k_scan_pass1<<<dim3(128 * NCH), 256, 0, stream>>>(delta, xc, xdbl, A_log,
                                                    scanP, scanS);
  k_scan_mid<<<dim3(LANES / 64), 64, 0, stream>>>(scanP, scanS);
  k_scan_pass2<<<dim3(128 * NCH), 256, 0, stream>>>(delta, xc, xdbl, A_log,
                                                    D_param, scanS, ybuf);
  k_gt<<<dim3(SEQ / 64, DIM / 64, BATCH), 256, 0, stream>>>(ybuf, zbuf,
                                                            gh, gl);
  kgemm_f16x3<0><<<dim3(8, 32), 256, 0, stream>>>(gh, gl, woh, wol,
                                                  out, nullptr);
}

// Round 7
// 388.251 us; speedup vs baseline: 1.3341x; 1.3341x over previous
//
#include <hip/hip_runtime.h>
#include <math.h>

#define BATCH 2
#define SEQ   2048
#define DIM   1024
#define NST   16
#define DTR   64
#define NCH   16                    // time chunks for the scan
#define CHUNK (SEQ / NCH)           // 128 steps per chunk
#define LANES (BATCH * DIM * NST)   // 32768 scan lanes
#define KSL   8                     // split-K slices for x_proj

typedef _Float16 f16x8 __attribute__((ext_vector_type(8)));
typedef float f32x4 __attribute__((ext_vector_type(4)));

__device__ __forceinline__ float softplus_f(float v) {
  return fmaxf(v, 0.f) + log1pf(expf(-fabsf(v)));
}
__device__ __forceinline__ float silu_f(float v) {
  return v / (1.f + expf(-v));
}

__device__ __forceinline__ void gl_lds16(const _Float16* g, _Float16* l) {
  __builtin_amdgcn_global_load_lds(
      (const __attribute__((address_space(1))) void*)g,
      (__attribute__((address_space(3))) void*)l, 16, 0, 0);
}

#define FMA_ROW(i, av)                                        \
  acc[i][0] = fmaf(av, b.x, acc[i][0]);                       \
  acc[i][1] = fmaf(av, b.y, acc[i][1]);                       \
  acc[i][2] = fmaf(av, b.z, acc[i][2]);                       \
  acc[i][3] = fmaf(av, b.w, acc[i][3]);

// ---------------- split fp32 -> hi/lo f16 planes ----------------
__global__ __launch_bounds__(256) void k_cvt(const float* __restrict__ in,
                                             _Float16* __restrict__ hi,
                                             _Float16* __restrict__ lo,
                                             int n) {
  const int i = (blockIdx.x * 256 + threadIdx.x) * 8;
  if (i >= n) return;
  const float4 a = *(const float4*)(in + i);
  const float4 b = *(const float4*)(in + i + 4);
  const float v[8] = {a.x, a.y, a.z, a.w, b.x, b.y, b.z, b.w};
  f16x8 h, l;
#pragma unroll
  for (int j = 0; j < 8; ++j) {
    const _Float16 hh = (_Float16)v[j];
    h[j] = hh;
    l[j] = (_Float16)(v[j] - (float)hh);
  }
  *(f16x8*)(hi + i) = h;
  *(f16x8*)(lo + i) = l;
}

// ---------------- f16x3 NT GEMM: D[m][n] = sum_k A[m,k]*B[n,k], K=LD=1024 ----
template <int EPI>
__global__ __launch_bounds__(256) void kgemm_f16x3(
    const _Float16* __restrict__ Ah, const _Float16* __restrict__ Al,
    const _Float16* __restrict__ Bh, const _Float16* __restrict__ Bl,
    float* __restrict__ out0, float* __restrict__ out1) {
  __shared__ _Float16 sm[16384];  // 32 KB: Ah|Al|Bh|Bl tiles, 128x32 packed
  _Float16* Ash = sm;
  _Float16* Asl = sm + 4096;
  _Float16* Bsh = sm + 8192;
  _Float16* Bsl = sm + 12288;

  const int tid = threadIdx.x;
  const int wid = tid >> 6, lane = tid & 63;
  const int wm = wid >> 1, wn = wid & 1;
  const int m0 = blockIdx.y * 128;
  const int n0 = blockIdx.x * 128;

  const int r0 = wid * 32;
  const int srow = lane >> 2;
  const int skq = (lane & 3) * 8;
  const _Float16* gAh = Ah + (size_t)(m0 + r0 + srow) * 1024 + skq;
  const _Float16* gAl = Al + (size_t)(m0 + r0 + srow) * 1024 + skq;
  const _Float16* gBh = Bh + (size_t)(n0 + r0 + srow) * 1024 + skq;
  const _Float16* gBl = Bl + (size_t)(n0 + r0 + srow) * 1024 + skq;
  _Float16* lAh = Ash + r0 * 32;
  _Float16* lAl = Asl + r0 * 32;
  _Float16* lBh = Bsh + r0 * 32;
  _Float16* lBl = Bsl + r0 * 32;

  const int fr = lane & 15;
  const int fk = (lane >> 4) * 8;

  f32x4 acc[4][4];
#pragma unroll
  for (int i = 0; i < 4; ++i)
#pragma unroll
    for (int j = 0; j < 4; ++j) acc[i][j] = (f32x4)(0.f);

  for (int k0 = 0; k0 < 1024; k0 += 32) {
    __syncthreads();
    gl_lds16(gAh + k0, lAh);
    gl_lds16(gAh + k0 + 16 * 1024, lAh + 512);
    gl_lds16(gAl + k0, lAl);
    gl_lds16(gAl + k0 + 16 * 1024, lAl + 512);
    gl_lds16(gBh + k0, lBh);
    gl_lds16(gBh + k0 + 16 * 1024, lBh + 512);
    gl_lds16(gBl + k0, lBl);
    gl_lds16(gBl + k0 + 16 * 1024, lBl + 512);
    __syncthreads();

    f16x8 ah[4], alo[4], bh[4], blo[4];
#pragma unroll
    for (int i = 0; i < 4; ++i) {
      const int ao = (wm * 64 + i * 16 + fr) * 32 + fk;
      const int bo = (wn * 64 + i * 16 + fr) * 32 + fk;
      ah[i]  = *(const f16x8*)(Ash + ao);
      alo[i] = *(const f16x8*)(Asl + ao);
      bh[i]  = *(const f16x8*)(Bsh + bo);
      blo[i] = *(const f16x8*)(Bsl + bo);
    }
#pragma unroll
    for (int i = 0; i < 4; ++i)
#pragma unroll
      for (int j = 0; j < 4; ++j) {
        acc[i][j] = __builtin_amdgcn_mfma_f32_16x16x32_f16(ah[i], bh[j],
                                                           acc[i][j], 0, 0, 0);
        acc[i][j] = __builtin_amdgcn_mfma_f32_16x16x32_f16(ah[i], blo[j],
                                                           acc[i][j], 0, 0, 0);
        acc[i][j] = __builtin_amdgcn_mfma_f32_16x16x32_f16(alo[i], bh[j],
                                                           acc[i][j], 0, 0, 0);
      }
  }

  const int lr4 = (lane >> 4) * 4, lc = lane & 15;
#pragma unroll
  for (int i = 0; i < 4; ++i) {
#pragma unroll
    for (int j = 0; j < 4; ++j) {
      const int ar = m0 + wm * 64 + i * 16 + lr4;
      const int bc = n0 + wn * 64 + j * 16 + lc;
#pragma unroll
      for (int r = 0; r < 4; ++r) {
        const float v = acc[i][j][r];
        if (EPI == 0) {
          out0[(size_t)(ar + r) * 1024 + bc] = v;
        } else {
          const int bb = bc >> 11, tt = bc & 2047;
          if (ar < 1024) {
            out0[((size_t)bb * 1024 + ar + r) * 2048 + tt] = v;
          } else {
            out1[((size_t)bb * 1024 + (ar + r - 1024)) * 2048 + tt] = v;
          }
        }
      }
    }
  }
}

// ---------------- conv: depthwise k=3, pad=1, along t ----------------
__global__ __launch_bounds__(256) void k_conv(
    const float* __restrict__ xcraw, const float* __restrict__ cw,
    const float* __restrict__ cb, float* __restrict__ xc) {
  const int idx = blockIdx.x * 256 + threadIdx.x;
  const int t0 = (idx & (SEQ / 4 - 1)) * 4;
  const int r = idx >> 9;  // b*DIM + d
  const int d = r & (DIM - 1);
  const float w0 = cw[d * 3 + 0], w1 = cw[d * 3 + 1], w2 = cw[d * 3 + 2];
  const float bias = cb[d];
  const float* in = xcraw + (size_t)r * SEQ;
  float o[4];
#pragma unroll
  for (int j = 0; j < 4; ++j) {
    const int t = t0 + j;
    const float xm = (t > 0) ? in[t - 1] : 0.f;
    const float x0 = in[t];
    const float xp = (t < SEQ - 1) ? in[t + 1] : 0.f;
    o[j] = fmaf(w0, xm, fmaf(w1, x0, fmaf(w2, xp, bias)));
  }
  *(float4*)(xc + (size_t)r * SEQ + t0) = make_float4(o[0], o[1], o[2], o[3]);
}

// ---------------- K2: x_proj split-K GEMM ----------------
__global__ __launch_bounds__(256) void k2_xproj_sk(
    const float* __restrict__ xc, const float* __restrict__ wp,
    float* __restrict__ part) {
  __shared__ float As[16][100];   // [kk][j], +4 pad
  __shared__ float Bs[16][132];   // [kk][t], +4 pad
  const int tid = threadIdx.x;
  const int tile = blockIdx.x;            // 0..31
  const int ks = blockIdx.y;              // 0..KSL-1
  const int b = tile >> 4;
  const int t0 = (tile & 15) * 128;
  const int kbase = ks * (DIM / KSL);     // 128-wide K slice
  const int tx = tid & 15, ty = tid >> 4;
  float acc[6][8] = {{0.f}};
  for (int k = 0; k < DIM / KSL; k += 16) {
    float a_reg[6];
#pragma unroll
    for (int i = 0; i < 6; ++i) {
      const int ii = tid + 256 * i;
      a_reg[i] = wp[(size_t)(ii >> 4) * DIM + kbase + k + (ii & 15)];
    }
    float4 b_reg[2];
#pragma unroll
    for (int r = 0; r < 2; ++r) {
      const int id2 = tid + 256 * r;
      const int krow = id2 >> 5, t4 = (id2 & 31) * 4;
      b_reg[r] = *(const float4*)(xc + ((size_t)b * DIM + kbase + k + krow) *
                                           SEQ + t0 + t4);
    }
    __syncthreads();
#pragma unroll
    for (int i = 0; i < 6; ++i) {
      const int ii = tid + 256 * i;
      As[ii & 15][ii >> 4] = a_reg[i];
    }
#pragma unroll
    for (int r = 0; r < 2; ++r) {
      const int id2 = tid + 256 * r;
      const int krow = id2 >> 5, t4 = (id2 & 31) * 4;
      *(float4*)&Bs[krow][t4] = b_reg[r];
    }
    __syncthreads();
#pragma unroll
    for (int kk = 0; kk < 16; ++kk) {
      const float4 bA = *(const float4*)&Bs[kk][tx * 4];
      const float4 bB = *(const float4*)&Bs[kk][64 + tx * 4];
#pragma unroll
      for (int i = 0; i < 6; ++i) {
        const float a = As[kk][ty + 16 * i];
        acc[i][0] = fmaf(a, bA.x, acc[i][0]);
        acc[i][1] = fmaf(a, bA.y, acc[i][1]);
        acc[i][2] = fmaf(a, bA.z, acc[i][2]);
        acc[i][3] = fmaf(a, bA.w, acc[i][3]);
        acc[i][4] = fmaf(a, bB.x, acc[i][4]);
        acc[i][5] = fmaf(a, bB.y, acc[i][5]);
        acc[i][6] = fmaf(a, bB.z, acc[i][6]);
        acc[i][7] = fmaf(a, bB.w, acc[i][7]);
      }
    }
    __syncthreads();
  }
#pragma unroll
  for (int i = 0; i < 6; ++i) {
    const int j = ty + 16 * i;
    const size_t o = ((size_t)(ks * BATCH + b) * 96 + j) * SEQ + t0;
    *(float4*)(part + o + tx * 4) =
        make_float4(acc[i][0], acc[i][1], acc[i][2], acc[i][3]);
    *(float4*)(part + o + 64 + tx * 4) =
        make_float4(acc[i][4], acc[i][5], acc[i][6], acc[i][7]);
  }
}

// ---------------- reduce split-K partials -> xdbl ----------------
__global__ __launch_bounds__(256) void k_red(const float* __restrict__ part,
                                             float* __restrict__ xdbl) {
  const size_t PL = (size_t)BATCH * 96 * SEQ;  // 393216
  const size_t i4 = ((size_t)blockIdx.x * 256 + threadIdx.x) * 4;
  float4 s = *(const float4*)(part + i4);
#pragma unroll
  for (int ks = 1; ks < KSL; ++ks) {
    const float4 v = *(const float4*)(part + ks * PL + i4);
    s.x += v.x; s.y += v.y; s.z += v.z; s.w += v.w;
  }
  *(float4*)(xdbl + i4) = s;
}

// ---------------- K3: dt_proj GEMM + softplus (fp32, small) ----------------
__global__ __launch_bounds__(256) void k3_dtproj(
    const float* __restrict__ xdbl, const float* __restrict__ dtw,
    const float* __restrict__ dtb, float* __restrict__ delta) {
  __shared__ float As[16][68];
  __shared__ float Bs[16][68];
  const int tid = threadIdx.x;
  const int b = blockIdx.z;
  const int d0 = blockIdx.y * 64;
  const int t0 = blockIdx.x * 64;
  const int tx = tid & 15, ty = tid >> 4;
  const int lrow = tid >> 2, lcol = (tid & 3) * 4;
  const int bk = tid >> 4, bt4 = (tid & 15) * 4;
  float acc[4][4] = {{0.f}};
  for (int k = 0; k < DTR; k += 16) {
    const float4 av =
        *(const float4*)(dtw + (size_t)(d0 + lrow) * DTR + k + lcol);
    const float4 bv =
        *(const float4*)(xdbl + ((size_t)b * 96 + k + bk) * SEQ + t0 + bt4);
    __syncthreads();
    As[lcol + 0][lrow] = av.x; As[lcol + 1][lrow] = av.y;
    As[lcol + 2][lrow] = av.z; As[lcol + 3][lrow] = av.w;
    Bs[bk][bt4 + 0] = bv.x; Bs[bk][bt4 + 1] = bv.y;
    Bs[bk][bt4 + 2] = bv.z; Bs[bk][bt4 + 3] = bv.w;
    __syncthreads();
#pragma unroll
    for (int kk = 0; kk < 16; ++kk) {
      const float4 a = *(const float4*)&As[kk][ty * 4];
      const float4 b = *(const float4*)&Bs[kk][tx * 4];
      FMA_ROW(0, a.x) FMA_ROW(1, a.y) FMA_ROW(2, a.z) FMA_ROW(3, a.w)
    }
  }
#pragma unroll
  for (int i = 0; i < 4; ++i) {
    const int d = d0 + ty * 4 + i;
    const float bias = dtb[d];
    float4 v;
    v.x = softplus_f(acc[i][0] + bias);
    v.y = softplus_f(acc[i][1] + bias);
    v.z = softplus_f(acc[i][2] + bias);
    v.w = softplus_f(acc[i][3] + bias);
    *(float4*)(delta + ((size_t)b * DIM + d) * SEQ + t0 + tx * 4) = v;
  }
}

// ---------------- scan pass 1: per-chunk product + local end state ----------
__global__ __launch_bounds__(256) void k_scan_pass1(
    const float* __restrict__ delta, const float* __restrict__ u,
    const float* __restrict__ xdbl, const float* __restrict__ A_log,
    float* __restrict__ Pbuf, float* __restrict__ Sbuf) {
  const int tid = threadIdx.x;
  const int gid = tid >> 4, n = tid & 15;
  const int bdblk = blockIdx.x & 127;
  const int chunk = blockIdx.x >> 7;
  const int idx = bdblk * 16 + gid;  // b*DIM + d
  const int b = idx >> 10, d = idx & (DIM - 1);
  const float A = -expf(A_log[d * NST + n]);
  const int tc = chunk * CHUNK;
  const float* drow = delta + (size_t)idx * SEQ + tc;
  const float* urow = u + (size_t)idx * SEQ + tc;
  const float* Brow = xdbl + ((size_t)b * 96 + DTR + n) * SEQ + tc;
  float s = 0.f, dsum = 0.f;
  for (int t0 = 0; t0 < CHUNK; t0 += 4) {
    const float4 dl = *(const float4*)(drow + t0);
    const float4 uu = *(const float4*)(urow + t0);
    const float4 Bv = *(const float4*)(Brow + t0);
    const float dls[4] = {dl.x, dl.y, dl.z, dl.w};
    const float us[4] = {uu.x, uu.y, uu.z, uu.w};
    const float Bb[4] = {Bv.x, Bv.y, Bv.z, Bv.w};
#pragma unroll
    for (int j = 0; j < 4; ++j) {
      dsum += dls[j];
      const float dA = __expf(dls[j] * A);
      s = fmaf(dA, s, dls[j] * us[j] * Bb[j]);
    }
  }
  const int gi = chunk * LANES + idx * 16 + n;
  Pbuf[gi] = __expf(dsum * A);
  Sbuf[gi] = s;
}

// ---------------- scan mid ----------------
__global__ __launch_bounds__(64) void k_scan_mid(
    const float* __restrict__ Pbuf, float* __restrict__ Sbuf) {
  const int gl = blockIdx.x * 64 + threadIdx.x;
  float run = 0.f;
#pragma unroll
  for (int c = 0; c < NCH; ++c) {
    const float p = Pbuf[c * LANES + gl];
    const float s = Sbuf[c * LANES + gl];
    Sbuf[c * LANES + gl] = run;
    run = fmaf(p, run, s);
  }
}

// ---------------- scan pass 2: seeded scan; LDS-transpose n-reduction -------
// 256 threads = 16 groups of 16 lanes; group = one (b,d) row.
// Per 16-t window: lane n accumulates c[t]=s*C (+u*D folded on n==0) in
// REGISTERS with static indices only, writes its column to LDS [t][n]
// (static t per store), reads back row t=n as 4x b128, linear sum.
// Wave-local LDS traffic (in-order DS pipe) needs no barrier.
__global__ __launch_bounds__(256, 8) void k_scan_pass2(
    const float* __restrict__ delta, const float* __restrict__ u,
    const float* __restrict__ xdbl, const float* __restrict__ A_log,
    const float* __restrict__ Dp, const float* __restrict__ sInit,
    float* __restrict__ y) {
  __shared__ float sc[16][16][20];  // 20 KB: [gid][t][n], pad 20 (16B-align rows)
  const int tid = threadIdx.x;
  const int n = tid & 15;
  const int gid = tid >> 4;          // 0..15
  const int bdblk = blockIdx.x & 127;
  const int chunk = blockIdx.x >> 7;
  const int idx = bdblk * 16 + gid;  // b*DIM + d
  const int b = idx >> 10, d = idx & (DIM - 1);
  const float A = -expf(A_log[d * NST + n]);
  const float Dprm = Dp[d];
  const int tc = chunk * CHUNK;
  const float* drow = delta + (size_t)idx * SEQ + tc;
  const float* urow = u + (size_t)idx * SEQ + tc;
  const float* Brow = xdbl + ((size_t)b * 96 + DTR + n) * SEQ + tc;
  const float* Crow = xdbl + ((size_t)b * 96 + DTR + NST + n) * SEQ + tc;
  float* yrow = y + (size_t)idx * SEQ + tc;
  float s = sInit[chunk * LANES + idx * 16 + n];
  for (int tw = 0; tw < CHUNK; tw += 16) {
#pragma unroll
    for (int q = 0; q < 4; ++q) {
      const int t0 = tw + q * 4;
      const float4 dl = *(const float4*)(drow + t0);
      const float4 uu = *(const float4*)(urow + t0);
      const float4 Bv = *(const float4*)(Brow + t0);
      const float4 Cv = *(const float4*)(Crow + t0);
      const float dls[4] = {dl.x, dl.y, dl.z, dl.w};
      const float us[4] = {uu.x, uu.y, uu.z, uu.w};
      const float Bb[4] = {Bv.x, Bv.y, Bv.z, Bv.w};
      const float Cc[4] = {Cv.x, Cv.y, Cv.z, Cv.w};
#pragma unroll
      for (int j = 0; j < 4; ++j) {
        const float dA = __expf(dls[j] * A);
        s = fmaf(dA, s, dls[j] * us[j] * Bb[j]);
        float cv = s * Cc[j];
        if (n == 0) cv = fmaf(us[j], Dprm, cv);
        sc[gid][q * 4 + j][n] = cv;   // static row index per store
      }
    }
    // gather row t=n (16B-aligned: n*80 bytes), linear sum
    const float4 r0 = *(const float4*)&sc[gid][n][0];
    const float4 r1 = *(const float4*)&sc[gid][n][4];
    const float4 r2 = *(const float4*)&sc[gid][n][8];
    const float4 r3 = *(const float4*)&sc[gid][n][12];
    const float sum = ((r0.x + r0.y) + (r0.z + r0.w)) +
                      ((r1.x + r1.y) + (r1.z + r1.w)) +
                      ((r2.x + r2.y) + (r2.z + r2.w)) +
                      ((r3.x + r3.y) + (r3.z + r3.w));
    yrow[tw + n] = sum;
  }
}

// ---------------- gate + transpose: g=(y*silu(z)) -> gh/gl (n,d) f16 --------
__global__ __launch_bounds__(256) void k_gt(
    const float* __restrict__ y, const float* __restrict__ z,
    _Float16* __restrict__ gh, _Float16* __restrict__ gl) {
  __shared__ _Float16 th[64][68];  // [d_local][t_local]
  __shared__ _Float16 tl[64][68];
  const int ti = threadIdx.x;
  const int t0 = blockIdx.x * 64;
  const int d0 = blockIdx.y * 64;
  const int b = blockIdx.z;
  const int c4 = (ti & 15) * 4;
#pragma unroll
  for (int rr = 0; rr < 4; ++rr) {
    const int dl_ = (ti >> 4) + 16 * rr;
    const size_t base = ((size_t)b * DIM + d0 + dl_) * SEQ + t0 + c4;
    const float4 yv = *(const float4*)(y + base);
    const float4 zv = *(const float4*)(z + base);
    const float gy[4] = {yv.x * silu_f(zv.x), yv.y * silu_f(zv.y),
                         yv.z * silu_f(zv.z), yv.w * silu_f(zv.w)};
#pragma unroll
    for (int k = 0; k < 4; ++k) {
      const _Float16 h = (_Float16)gy[k];
      th[dl_][c4 + k] = h;
      tl[dl_][c4 + k] = (_Float16)(gy[k] - (float)h);
    }
  }
  __syncthreads();
#pragma unroll
  for (int rr = 0; rr < 2; ++rr) {
    const int chunk = ti + 256 * rr;
    const int tloc = chunk >> 3;
    const int dchunk = (chunk & 7) * 8;
    f16x8 hv, lv;
#pragma unroll
    for (int j = 0; j < 8; ++j) {
      hv[j] = th[dchunk + j][tloc];
      lv[j] = tl[dchunk + j][tloc];
    }
    const size_t o = ((size_t)b * SEQ + t0 + tloc) * DIM + d0 + dchunk;
    *(f16x8*)(gh + o) = hv;
    *(f16x8*)(gl + o) = lv;
  }
}

extern "C" void kernel_launch(void* const* d_in, const int* in_sizes, int n_in,
                              void* d_out, int out_size, void* d_ws,
                              size_t ws_size, hipStream_t stream) {
  const float* x          = (const float*)d_in[0];
  const float* in_proj_w  = (const float*)d_in[1];
  const float* conv_w     = (const float*)d_in[2];
  const float* conv_b     = (const float*)d_in[3];
  const float* A_log      = (const float*)d_in[4];
  const float* D_param    = (const float*)d_in[5];
  const float* x_proj_w   = (const float*)d_in[6];
  const float* dt_proj_w  = (const float*)d_in[7];
  const float* dt_proj_b  = (const float*)d_in[8];
  const float* out_proj_w = (const float*)d_in[9];
  float* out = (float*)d_out;
  float* ws = (float*)d_ws;

  const size_t PLANE = (size_t)BATCH * SEQ * DIM;  // 4M floats (16 MB)
  float* xcraw = ws;
  float* delta = ws;
  _Float16* gh = (_Float16*)ws;                    // PLANE f16
  _Float16* gl = (_Float16*)ws + PLANE;            // PLANE f16
  float* xc    = ws + PLANE;      // (b,d,t) post-conv
  float* zbuf  = ws + 2 * PLANE;  // (b,dz,t) channel-major
  _Float16* xh = (_Float16*)(ws + 3 * PLANE);
  _Float16* xl = xh + PLANE;
  float* part  = ws + 3 * PLANE;   // KSL * 393216 = 3.1M floats
  float* ybuf  = ws + 3 * PLANE;
  float* xdbl  = ws + 4 * PLANE;                    // (b,96,t) 393216 floats
  float* scanP = xdbl + (size_t)BATCH * 96 * SEQ;   // 524288 floats
  float* scanS = scanP + (size_t)LANES * NCH;       // 524288 floats
  _Float16* wih = (_Float16*)(ws + 4 * PLANE + 1572864);
  _Float16* wil = wih + (size_t)2 * DIM * DIM;
  _Float16* woh = wil + (size_t)2 * DIM * DIM;
  _Float16* wol = woh + (size_t)DIM * DIM;

  k_cvt<<<dim3(2048), 256, 0, stream>>>(x, xh, xl, BATCH * SEQ * DIM);
  k_cvt<<<dim3(1024), 256, 0, stream>>>(in_proj_w, wih, wil, 2 * DIM * DIM);
  k_cvt<<<dim3(512), 256, 0, stream>>>(out_proj_w, woh, wol, DIM * DIM);

  kgemm_f16x3<1><<<dim3(32, 16), 256, 0, stream>>>(wih, wil, xh, xl,
                                                   xcraw, zbuf);
  k_conv<<<dim3((BATCH * DIM * SEQ / 4) / 256), 256, 0, stream>>>(
      xcraw, conv_w, conv_b, xc);
  k2_xproj_sk<<<dim3(32, KSL), 256, 0, stream>>>(xc, x_proj_w, part);
  k_red<<<dim3(384), 256, 0, stream>>>(part, xdbl);
  k3_dtproj<<<dim3(SEQ / 64, DIM / 64, BATCH), 256, 0, stream>>>(
      xdbl, dt_proj_w, dt_proj_b, delta);
  k_scan_pass1<<<dim3(128 * NCH), 256, 0, stream>>>(delta, xc, xdbl, A_log,
                                                    scanP, scanS);
  k_scan_mid<<<dim3(LANES / 64), 64, 0, stream>>>(scanP, scanS);
  k_scan_pass2<<<dim3(128 * NCH), 256, 0, stream>>>(delta, xc, xdbl, A_log,
                                                    D_param, scanS, ybuf);
  k_gt<<<dim3(SEQ / 64, DIM / 64, BATCH), 256, 0, stream>>>(ybuf, zbuf,
                                                            gh, gl);
  kgemm_f16x3<0><<<dim3(8, 32), 256, 0, stream>>>(gh, gl, woh, wol,
                                                  out, nullptr);
}

// Round 8
// 380.005 us; speedup vs baseline: 1.3631x; 1.0217x over previous
//
#include <hip/hip_runtime.h>
#include <math.h>

#define BATCH 2
#define SEQ   2048
#define DIM   1024
#define NST   16
#define DTR   64
#define NCH   16                    // time chunks for the scan
#define CHUNK (SEQ / NCH)           // 128 steps per chunk
#define LANES (BATCH * DIM * NST)   // 32768 scan lanes
#define KSL   8                     // split-K slices for x_proj

typedef _Float16 f16x8 __attribute__((ext_vector_type(8)));
typedef float f32x4 __attribute__((ext_vector_type(4)));

__device__ __forceinline__ float softplus_f(float v) {
  return fmaxf(v, 0.f) + log1pf(expf(-fabsf(v)));
}
__device__ __forceinline__ float silu_f(float v) {
  return v / (1.f + expf(-v));
}

__device__ __forceinline__ void gl_lds16(const _Float16* g, _Float16* l) {
  __builtin_amdgcn_global_load_lds(
      (const __attribute__((address_space(1))) void*)g,
      (__attribute__((address_space(3))) void*)l, 16, 0, 0);
}

#define FMA_ROW(i, av)                                        \
  acc[i][0] = fmaf(av, b.x, acc[i][0]);                       \
  acc[i][1] = fmaf(av, b.y, acc[i][1]);                       \
  acc[i][2] = fmaf(av, b.z, acc[i][2]);                       \
  acc[i][3] = fmaf(av, b.w, acc[i][3]);

// ---------------- split fp32 -> hi/lo f16 planes ----------------
__global__ __launch_bounds__(256) void k_cvt(const float* __restrict__ in,
                                             _Float16* __restrict__ hi,
                                             _Float16* __restrict__ lo,
                                             int n) {
  const int i = (blockIdx.x * 256 + threadIdx.x) * 8;
  if (i >= n) return;
  const float4 a = *(const float4*)(in + i);
  const float4 b = *(const float4*)(in + i + 4);
  const float v[8] = {a.x, a.y, a.z, a.w, b.x, b.y, b.z, b.w};
  f16x8 h, l;
#pragma unroll
  for (int j = 0; j < 8; ++j) {
    const _Float16 hh = (_Float16)v[j];
    h[j] = hh;
    l[j] = (_Float16)(v[j] - (float)hh);
  }
  *(f16x8*)(hi + i) = h;
  *(f16x8*)(lo + i) = l;
}

// ---------------- f16x3 NT GEMM: D[m][n] = sum_k A[m,k]*B[n,k], K=LD=1024 ----
template <int EPI>
__global__ __launch_bounds__(256) void kgemm_f16x3(
    const _Float16* __restrict__ Ah, const _Float16* __restrict__ Al,
    const _Float16* __restrict__ Bh, const _Float16* __restrict__ Bl,
    float* __restrict__ out0, float* __restrict__ out1) {
  __shared__ _Float16 sm[16384];  // 32 KB: Ah|Al|Bh|Bl tiles, 128x32 packed
  _Float16* Ash = sm;
  _Float16* Asl = sm + 4096;
  _Float16* Bsh = sm + 8192;
  _Float16* Bsl = sm + 12288;

  const int tid = threadIdx.x;
  const int wid = tid >> 6, lane = tid & 63;
  const int wm = wid >> 1, wn = wid & 1;
  const int m0 = blockIdx.y * 128;
  const int n0 = blockIdx.x * 128;

  const int r0 = wid * 32;
  const int srow = lane >> 2;
  const int skq = (lane & 3) * 8;
  const _Float16* gAh = Ah + (size_t)(m0 + r0 + srow) * 1024 + skq;
  const _Float16* gAl = Al + (size_t)(m0 + r0 + srow) * 1024 + skq;
  const _Float16* gBh = Bh + (size_t)(n0 + r0 + srow) * 1024 + skq;
  const _Float16* gBl = Bl + (size_t)(n0 + r0 + srow) * 1024 + skq;
  _Float16* lAh = Ash + r0 * 32;
  _Float16* lAl = Asl + r0 * 32;
  _Float16* lBh = Bsh + r0 * 32;
  _Float16* lBl = Bsl + r0 * 32;

  const int fr = lane & 15;
  const int fk = (lane >> 4) * 8;

  f32x4 acc[4][4];
#pragma unroll
  for (int i = 0; i < 4; ++i)
#pragma unroll
    for (int j = 0; j < 4; ++j) acc[i][j] = (f32x4)(0.f);

  for (int k0 = 0; k0 < 1024; k0 += 32) {
    __syncthreads();
    gl_lds16(gAh + k0, lAh);
    gl_lds16(gAh + k0 + 16 * 1024, lAh + 512);
    gl_lds16(gAl + k0, lAl);
    gl_lds16(gAl + k0 + 16 * 1024, lAl + 512);
    gl_lds16(gBh + k0, lBh);
    gl_lds16(gBh + k0 + 16 * 1024, lBh + 512);
    gl_lds16(gBl + k0, lBl);
    gl_lds16(gBl + k0 + 16 * 1024, lBl + 512);
    __syncthreads();

    f16x8 ah[4], alo[4], bh[4], blo[4];
#pragma unroll
    for (int i = 0; i < 4; ++i) {
      const int ao = (wm * 64 + i * 16 + fr) * 32 + fk;
      const int bo = (wn * 64 + i * 16 + fr) * 32 + fk;
      ah[i]  = *(const f16x8*)(Ash + ao);
      alo[i] = *(const f16x8*)(Asl + ao);
      bh[i]  = *(const f16x8*)(Bsh + bo);
      blo[i] = *(const f16x8*)(Bsl + bo);
    }
#pragma unroll
    for (int i = 0; i < 4; ++i)
#pragma unroll
      for (int j = 0; j < 4; ++j) {
        acc[i][j] = __builtin_amdgcn_mfma_f32_16x16x32_f16(ah[i], bh[j],
                                                           acc[i][j], 0, 0, 0);
        acc[i][j] = __builtin_amdgcn_mfma_f32_16x16x32_f16(ah[i], blo[j],
                                                           acc[i][j], 0, 0, 0);
        acc[i][j] = __builtin_amdgcn_mfma_f32_16x16x32_f16(alo[i], bh[j],
                                                           acc[i][j], 0, 0, 0);
      }
  }

  const int lr4 = (lane >> 4) * 4, lc = lane & 15;
#pragma unroll
  for (int i = 0; i < 4; ++i) {
#pragma unroll
    for (int j = 0; j < 4; ++j) {
      const int ar = m0 + wm * 64 + i * 16 + lr4;
      const int bc = n0 + wn * 64 + j * 16 + lc;
#pragma unroll
      for (int r = 0; r < 4; ++r) {
        const float v = acc[i][j][r];
        if (EPI == 0) {
          out0[(size_t)(ar + r) * 1024 + bc] = v;
        } else {
          const int bb = bc >> 11, tt = bc & 2047;
          if (ar < 1024) {
            out0[((size_t)bb * 1024 + ar + r) * 2048 + tt] = v;
          } else {
            out1[((size_t)bb * 1024 + (ar + r - 1024)) * 2048 + tt] = v;
          }
        }
      }
    }
  }
}

// ---------------- conv: depthwise k=3, pad=1, along t ----------------
__global__ __launch_bounds__(256) void k_conv(
    const float* __restrict__ xcraw, const float* __restrict__ cw,
    const float* __restrict__ cb, float* __restrict__ xc) {
  const int idx = blockIdx.x * 256 + threadIdx.x;
  const int t0 = (idx & (SEQ / 4 - 1)) * 4;
  const int r = idx >> 9;  // b*DIM + d
  const int d = r & (DIM - 1);
  const float w0 = cw[d * 3 + 0], w1 = cw[d * 3 + 1], w2 = cw[d * 3 + 2];
  const float bias = cb[d];
  const float* in = xcraw + (size_t)r * SEQ;
  float o[4];
#pragma unroll
  for (int j = 0; j < 4; ++j) {
    const int t = t0 + j;
    const float xm = (t > 0) ? in[t - 1] : 0.f;
    const float x0 = in[t];
    const float xp = (t < SEQ - 1) ? in[t + 1] : 0.f;
    o[j] = fmaf(w0, xm, fmaf(w1, x0, fmaf(w2, xp, bias)));
  }
  *(float4*)(xc + (size_t)r * SEQ + t0) = make_float4(o[0], o[1], o[2], o[3]);
}

// ---------------- K2: x_proj split-K GEMM ----------------
__global__ __launch_bounds__(256) void k2_xproj_sk(
    const float* __restrict__ xc, const float* __restrict__ wp,
    float* __restrict__ part) {
  __shared__ float As[16][100];   // [kk][j], +4 pad
  __shared__ float Bs[16][132];   // [kk][t], +4 pad
  const int tid = threadIdx.x;
  const int tile = blockIdx.x;            // 0..31
  const int ks = blockIdx.y;              // 0..KSL-1
  const int b = tile >> 4;
  const int t0 = (tile & 15) * 128;
  const int kbase = ks * (DIM / KSL);     // 128-wide K slice
  const int tx = tid & 15, ty = tid >> 4;
  float acc[6][8] = {{0.f}};
  for (int k = 0; k < DIM / KSL; k += 16) {
    float a_reg[6];
#pragma unroll
    for (int i = 0; i < 6; ++i) {
      const int ii = tid + 256 * i;
      a_reg[i] = wp[(size_t)(ii >> 4) * DIM + kbase + k + (ii & 15)];
    }
    float4 b_reg[2];
#pragma unroll
    for (int r = 0; r < 2; ++r) {
      const int id2 = tid + 256 * r;
      const int krow = id2 >> 5, t4 = (id2 & 31) * 4;
      b_reg[r] = *(const float4*)(xc + ((size_t)b * DIM + kbase + k + krow) *
                                           SEQ + t0 + t4);
    }
    __syncthreads();
#pragma unroll
    for (int i = 0; i < 6; ++i) {
      const int ii = tid + 256 * i;
      As[ii & 15][ii >> 4] = a_reg[i];
    }
#pragma unroll
    for (int r = 0; r < 2; ++r) {
      const int id2 = tid + 256 * r;
      const int krow = id2 >> 5, t4 = (id2 & 31) * 4;
      *(float4*)&Bs[krow][t4] = b_reg[r];
    }
    __syncthreads();
#pragma unroll
    for (int kk = 0; kk < 16; ++kk) {
      const float4 bA = *(const float4*)&Bs[kk][tx * 4];
      const float4 bB = *(const float4*)&Bs[kk][64 + tx * 4];
#pragma unroll
      for (int i = 0; i < 6; ++i) {
        const float a = As[kk][ty + 16 * i];
        acc[i][0] = fmaf(a, bA.x, acc[i][0]);
        acc[i][1] = fmaf(a, bA.y, acc[i][1]);
        acc[i][2] = fmaf(a, bA.z, acc[i][2]);
        acc[i][3] = fmaf(a, bA.w, acc[i][3]);
        acc[i][4] = fmaf(a, bB.x, acc[i][4]);
        acc[i][5] = fmaf(a, bB.y, acc[i][5]);
        acc[i][6] = fmaf(a, bB.z, acc[i][6]);
        acc[i][7] = fmaf(a, bB.w, acc[i][7]);
      }
    }
    __syncthreads();
  }
#pragma unroll
  for (int i = 0; i < 6; ++i) {
    const int j = ty + 16 * i;
    const size_t o = ((size_t)(ks * BATCH + b) * 96 + j) * SEQ + t0;
    *(float4*)(part + o + tx * 4) =
        make_float4(acc[i][0], acc[i][1], acc[i][2], acc[i][3]);
    *(float4*)(part + o + 64 + tx * 4) =
        make_float4(acc[i][4], acc[i][5], acc[i][6], acc[i][7]);
  }
}

// ---------------- reduce split-K partials -> xdbl ----------------
__global__ __launch_bounds__(256) void k_red(const float* __restrict__ part,
                                             float* __restrict__ xdbl) {
  const size_t PL = (size_t)BATCH * 96 * SEQ;  // 393216
  const size_t i4 = ((size_t)blockIdx.x * 256 + threadIdx.x) * 4;
  float4 s = *(const float4*)(part + i4);
#pragma unroll
  for (int ks = 1; ks < KSL; ++ks) {
    const float4 v = *(const float4*)(part + ks * PL + i4);
    s.x += v.x; s.y += v.y; s.z += v.z; s.w += v.w;
  }
  *(float4*)(xdbl + i4) = s;
}

// ---------------- K3: dt_proj GEMM + softplus (fp32, small) ----------------
__global__ __launch_bounds__(256) void k3_dtproj(
    const float* __restrict__ xdbl, const float* __restrict__ dtw,
    const float* __restrict__ dtb, float* __restrict__ delta) {
  __shared__ float As[16][68];
  __shared__ float Bs[16][68];
  const int tid = threadIdx.x;
  const int b = blockIdx.z;
  const int d0 = blockIdx.y * 64;
  const int t0 = blockIdx.x * 64;
  const int tx = tid & 15, ty = tid >> 4;
  const int lrow = tid >> 2, lcol = (tid & 3) * 4;
  const int bk = tid >> 4, bt4 = (tid & 15) * 4;
  float acc[4][4] = {{0.f}};
  for (int k = 0; k < DTR; k += 16) {
    const float4 av =
        *(const float4*)(dtw + (size_t)(d0 + lrow) * DTR + k + lcol);
    const float4 bv =
        *(const float4*)(xdbl + ((size_t)b * 96 + k + bk) * SEQ + t0 + bt4);
    __syncthreads();
    As[lcol + 0][lrow] = av.x; As[lcol + 1][lrow] = av.y;
    As[lcol + 2][lrow] = av.z; As[lcol + 3][lrow] = av.w;
    Bs[bk][bt4 + 0] = bv.x; Bs[bk][bt4 + 1] = bv.y;
    Bs[bk][bt4 + 2] = bv.z; Bs[bk][bt4 + 3] = bv.w;
    __syncthreads();
#pragma unroll
    for (int kk = 0; kk < 16; ++kk) {
      const float4 a = *(const float4*)&As[kk][ty * 4];
      const float4 b = *(const float4*)&Bs[kk][tx * 4];
      FMA_ROW(0, a.x) FMA_ROW(1, a.y) FMA_ROW(2, a.z) FMA_ROW(3, a.w)
    }
  }
#pragma unroll
  for (int i = 0; i < 4; ++i) {
    const int d = d0 + ty * 4 + i;
    const float bias = dtb[d];
    float4 v;
    v.x = softplus_f(acc[i][0] + bias);
    v.y = softplus_f(acc[i][1] + bias);
    v.z = softplus_f(acc[i][2] + bias);
    v.w = softplus_f(acc[i][3] + bias);
    *(float4*)(delta + ((size_t)b * DIM + d) * SEQ + t0 + tx * 4) = v;
  }
}

// ---------------- scan pass 1: per-chunk product + local end state ----------
// 2-deep software pipeline on the 3 input streams (ILP over latency).
__global__ __launch_bounds__(256, 4) void k_scan_pass1(
    const float* __restrict__ delta, const float* __restrict__ u,
    const float* __restrict__ xdbl, const float* __restrict__ A_log,
    float* __restrict__ Pbuf, float* __restrict__ Sbuf) {
  const int tid = threadIdx.x;
  const int gid = tid >> 4, n = tid & 15;
  const int bdblk = blockIdx.x & 127;
  const int chunk = blockIdx.x >> 7;
  const int idx = bdblk * 16 + gid;  // b*DIM + d
  const int b = idx >> 10, d = idx & (DIM - 1);
  const float A = -expf(A_log[d * NST + n]);
  const int tc = chunk * CHUNK;
  const float* drow = delta + (size_t)idx * SEQ + tc;
  const float* urow = u + (size_t)idx * SEQ + tc;
  const float* Brow = xdbl + ((size_t)b * 96 + DTR + n) * SEQ + tc;
  float s = 0.f, dsum = 0.f;
  float4 d0v = *(const float4*)(drow);
  float4 u0v = *(const float4*)(urow);
  float4 B0v = *(const float4*)(Brow);
  float4 d1v = *(const float4*)(drow + 4);
  float4 u1v = *(const float4*)(urow + 4);
  float4 B1v = *(const float4*)(Brow + 4);
#pragma unroll 4
  for (int t0 = 0; t0 < CHUNK; t0 += 4) {
    const float4 dl = d0v, uu = u0v, Bv = B0v;
    d0v = d1v; u0v = u1v; B0v = B1v;
    if (t0 + 8 < CHUNK) {
      d1v = *(const float4*)(drow + t0 + 8);
      u1v = *(const float4*)(urow + t0 + 8);
      B1v = *(const float4*)(Brow + t0 + 8);
    }
    const float dls[4] = {dl.x, dl.y, dl.z, dl.w};
    const float us[4] = {uu.x, uu.y, uu.z, uu.w};
    const float Bb[4] = {Bv.x, Bv.y, Bv.z, Bv.w};
#pragma unroll
    for (int j = 0; j < 4; ++j) {
      dsum += dls[j];
      const float dA = __expf(dls[j] * A);
      s = fmaf(dA, s, dls[j] * us[j] * Bb[j]);
    }
  }
  const int gi = chunk * LANES + idx * 16 + n;
  Pbuf[gi] = __expf(dsum * A);
  Sbuf[gi] = s;
}

// ---------------- scan mid ----------------
__global__ __launch_bounds__(64) void k_scan_mid(
    const float* __restrict__ Pbuf, float* __restrict__ Sbuf) {
  const int gl = blockIdx.x * 64 + threadIdx.x;
  float run = 0.f;
#pragma unroll
  for (int c = 0; c < NCH; ++c) {
    const float p = Pbuf[c * LANES + gl];
    const float s = Sbuf[c * LANES + gl];
    Sbuf[c * LANES + gl] = run;
    run = fmaf(p, run, s);
  }
}

// ---------------- scan pass 2: seeded scan; LDS-transpose n-reduction -------
// 256 threads = 16 groups of 16 lanes; group = one (b,d) row.
// 2-deep software pipeline on the 4 input streams (launch_bounds (256,4)
// gives the register budget; R7's (256,8) forced VGPR=32 and serialized
// the loads). Group LDS stride 328 floats (8-bank rotation per gid) makes
// the 16-lane column writes 2-way across the wave's 4 groups (free).
__global__ __launch_bounds__(256, 4) void k_scan_pass2(
    const float* __restrict__ delta, const float* __restrict__ u,
    const float* __restrict__ xdbl, const float* __restrict__ A_log,
    const float* __restrict__ Dp, const float* __restrict__ sInit,
    float* __restrict__ y) {
  __shared__ float sc[16 * 328];     // 21 KB; group g at offset g*328
  const int tid = threadIdx.x;
  const int n = tid & 15;
  const int gid = tid >> 4;          // 0..15
  float* scg = sc + gid * 328;
  const int bdblk = blockIdx.x & 127;
  const int chunk = blockIdx.x >> 7;
  const int idx = bdblk * 16 + gid;  // b*DIM + d
  const int b = idx >> 10, d = idx & (DIM - 1);
  const float A = -expf(A_log[d * NST + n]);
  const float Dprm = Dp[d];
  const int tc = chunk * CHUNK;
  const float* drow = delta + (size_t)idx * SEQ + tc;
  const float* urow = u + (size_t)idx * SEQ + tc;
  const float* Brow = xdbl + ((size_t)b * 96 + DTR + n) * SEQ + tc;
  const float* Crow = xdbl + ((size_t)b * 96 + DTR + NST + n) * SEQ + tc;
  float* yrow = y + (size_t)idx * SEQ + tc;
  float s = sInit[chunk * LANES + idx * 16 + n];

  float4 p0[4], p1[4];  // 2-deep q pipeline: {dl, uu, Bv, Cv}
  p0[0] = *(const float4*)(drow);
  p0[1] = *(const float4*)(urow);
  p0[2] = *(const float4*)(Brow);
  p0[3] = *(const float4*)(Crow);
  p1[0] = *(const float4*)(drow + 4);
  p1[1] = *(const float4*)(urow + 4);
  p1[2] = *(const float4*)(Brow + 4);
  p1[3] = *(const float4*)(Crow + 4);

  for (int tw = 0; tw < CHUNK; tw += 16) {
#pragma unroll
    for (int q = 0; q < 4; ++q) {
      const float4 dl = p0[0], uu = p0[1], Bv = p0[2], Cv = p0[3];
      p0[0] = p1[0]; p0[1] = p1[1]; p0[2] = p1[2]; p0[3] = p1[3];
      const int tn = tw + q * 4 + 8;
      if (tn < CHUNK) {
        p1[0] = *(const float4*)(drow + tn);
        p1[1] = *(const float4*)(urow + tn);
        p1[2] = *(const float4*)(Brow + tn);
        p1[3] = *(const float4*)(Crow + tn);
      }
      const float dls[4] = {dl.x, dl.y, dl.z, dl.w};
      const float us[4] = {uu.x, uu.y, uu.z, uu.w};
      const float Bb[4] = {Bv.x, Bv.y, Bv.z, Bv.w};
      const float Cc[4] = {Cv.x, Cv.y, Cv.z, Cv.w};
#pragma unroll
      for (int j = 0; j < 4; ++j) {
        const float dA = __expf(dls[j] * A);
        s = fmaf(dA, s, dls[j] * us[j] * Bb[j]);
        float cv = s * Cc[j];
        if (n == 0) cv = fmaf(us[j], Dprm, cv);
        scg[(q * 4 + j) * 20 + n] = cv;   // static row index per store
      }
    }
    // gather row t=n (16B-aligned: n*20 floats), linear sum
    const float4 r0 = *(const float4*)&scg[n * 20 + 0];
    const float4 r1 = *(const float4*)&scg[n * 20 + 4];
    const float4 r2 = *(const float4*)&scg[n * 20 + 8];
    const float4 r3 = *(const float4*)&scg[n * 20 + 12];
    const float sum = ((r0.x + r0.y) + (r0.z + r0.w)) +
                      ((r1.x + r1.y) + (r1.z + r1.w)) +
                      ((r2.x + r2.y) + (r2.z + r2.w)) +
                      ((r3.x + r3.y) + (r3.z + r3.w));
    yrow[tw + n] = sum;
  }
}

// ---------------- gate + transpose: g=(y*silu(z)) -> gh/gl (n,d) f16 --------
__global__ __launch_bounds__(256) void k_gt(
    const float* __restrict__ y, const float* __restrict__ z,
    _Float16* __restrict__ gh, _Float16* __restrict__ gl) {
  __shared__ _Float16 th[64][68];  // [d_local][t_local]
  __shared__ _Float16 tl[64][68];
  const int ti = threadIdx.x;
  const int t0 = blockIdx.x * 64;
  const int d0 = blockIdx.y * 64;
  const int b = blockIdx.z;
  const int c4 = (ti & 15) * 4;
#pragma unroll
  for (int rr = 0; rr < 4; ++rr) {
    const int dl_ = (ti >> 4) + 16 * rr;
    const size_t base = ((size_t)b * DIM + d0 + dl_) * SEQ + t0 + c4;
    const float4 yv = *(const float4*)(y + base);
    const float4 zv = *(const float4*)(z + base);
    const float gy[4] = {yv.x * silu_f(zv.x), yv.y * silu_f(zv.y),
                         yv.z * silu_f(zv.z), yv.w * silu_f(zv.w)};
#pragma unroll
    for (int k = 0; k < 4; ++k) {
      const _Float16 h = (_Float16)gy[k];
      th[dl_][c4 + k] = h;
      tl[dl_][c4 + k] = (_Float16)(gy[k] - (float)h);
    }
  }
  __syncthreads();
#pragma unroll
  for (int rr = 0; rr < 2; ++rr) {
    const int chunk = ti + 256 * rr;
    const int tloc = chunk >> 3;
    const int dchunk = (chunk & 7) * 8;
    f16x8 hv, lv;
#pragma unroll
    for (int j = 0; j < 8; ++j) {
      hv[j] = th[dchunk + j][tloc];
      lv[j] = tl[dchunk + j][tloc];
    }
    const size_t o = ((size_t)b * SEQ + t0 + tloc) * DIM + d0 + dchunk;
    *(f16x8*)(gh + o) = hv;
    *(f16x8*)(gl + o) = lv;
  }
}

extern "C" void kernel_launch(void* const* d_in, const int* in_sizes, int n_in,
                              void* d_out, int out_size, void* d_ws,
                              size_t ws_size, hipStream_t stream) {
  const float* x          = (const float*)d_in[0];
  const float* in_proj_w  = (const float*)d_in[1];
  const float* conv_w     = (const float*)d_in[2];
  const float* conv_b     = (const float*)d_in[3];
  const float* A_log      = (const float*)d_in[4];
  const float* D_param    = (const float*)d_in[5];
  const float* x_proj_w   = (const float*)d_in[6];
  const float* dt_proj_w  = (const float*)d_in[7];
  const float* dt_proj_b  = (const float*)d_in[8];
  const float* out_proj_w = (const float*)d_in[9];
  float* out = (float*)d_out;
  float* ws = (float*)d_ws;

  const size_t PLANE = (size_t)BATCH * SEQ * DIM;  // 4M floats (16 MB)
  float* xcraw = ws;
  float* delta = ws;
  _Float16* gh = (_Float16*)ws;                    // PLANE f16
  _Float16* gl = (_Float16*)ws + PLANE;            // PLANE f16
  float* xc    = ws + PLANE;      // (b,d,t) post-conv
  float* zbuf  = ws + 2 * PLANE;  // (b,dz,t) channel-major
  _Float16* xh = (_Float16*)(ws + 3 * PLANE);
  _Float16* xl = xh + PLANE;
  float* part  = ws + 3 * PLANE;   // KSL * 393216 = 3.1M floats
  float* ybuf  = ws + 3 * PLANE;
  float* xdbl  = ws + 4 * PLANE;                    // (b,96,t) 393216 floats
  float* scanP = xdbl + (size_t)BATCH * 96 * SEQ;   // 524288 floats
  float* scanS = scanP + (size_t)LANES * NCH;       // 524288 floats
  _Float16* wih = (_Float16*)(ws + 4 * PLANE + 1572864);
  _Float16* wil = wih + (size_t)2 * DIM * DIM;
  _Float16* woh = wil + (size_t)2 * DIM * DIM;
  _Float16* wol = woh + (size_t)DIM * DIM;

  k_cvt<<<dim3(2048), 256, 0, stream>>>(x, xh, xl, BATCH * SEQ * DIM);
  k_cvt<<<dim3(1024), 256, 0, stream>>>(in_proj_w, wih, wil, 2 * DIM * DIM);
  k_cvt<<<dim3(512), 256, 0, stream>>>(out_proj_w, woh, wol, DIM * DIM);

  kgemm_f16x3<1><<<dim3(32, 16), 256, 0, stream>>>(wih, wil, xh, xl,
                                                   xcraw, zbuf);
  k_conv<<<dim3((BATCH * DIM * SEQ / 4) / 256), 256, 0, stream>>>(
      xcraw, conv_w, conv_b, xc);
  k2_xproj_sk<<<dim3(32, KSL), 256, 0, stream>>>(xc, x_proj_w, part);
  k_red<<<dim3(384), 256, 0, stream>>>(part, xdbl);
  k3_dtproj<<<dim3(SEQ / 64, DIM / 64, BATCH), 256, 0, stream>>>(
      xdbl, dt_proj_w, dt_proj_b, delta);
  k_scan_pass1<<<dim3(128 * NCH), 256, 0, stream>>>(delta, xc, xdbl, A_log,
                                                    scanP, scanS);
  k_scan_mid<<<dim3(LANES / 64), 64, 0, stream>>>(scanP, scanS);
  k_scan_pass2<<<dim3(128 * NCH), 256, 0, stream>>>(delta, xc, xdbl, A_log,
                                                    D_param, scanS, ybuf);
  k_gt<<<dim3(SEQ / 64, DIM / 64, BATCH), 256, 0, stream>>>(ybuf, zbuf,
                                                            gh, gl);
  kgemm_f16x3<0><<<dim3(8, 32), 256, 0, stream>>>(gh, gl, woh, wol,
                                                  out, nullptr);
}

// Round 9
// 318.844 us; speedup vs baseline: 1.6245x; 1.1918x over previous
//
#include <hip/hip_runtime.h>
#include <math.h>

#define BATCH 2
#define SEQ   2048
#define DIM   1024
#define NST   16
#define DTR   64
#define KSL   8                     // split-K slices for x_proj

typedef _Float16 f16x8 __attribute__((ext_vector_type(8)));
typedef float f32x4 __attribute__((ext_vector_type(4)));

__device__ __forceinline__ float softplus_f(float v) {
  return fmaxf(v, 0.f) + log1pf(expf(-fabsf(v)));
}
__device__ __forceinline__ float silu_f(float v) {
  return v / (1.f + expf(-v));
}

__device__ __forceinline__ void gl_lds16(const _Float16* g, _Float16* l) {
  __builtin_amdgcn_global_load_lds(
      (const __attribute__((address_space(1))) void*)g,
      (__attribute__((address_space(3))) void*)l, 16, 0, 0);
}

#define FMA_ROW(i, av)                                        \
  acc[i][0] = fmaf(av, b.x, acc[i][0]);                       \
  acc[i][1] = fmaf(av, b.y, acc[i][1]);                       \
  acc[i][2] = fmaf(av, b.z, acc[i][2]);                       \
  acc[i][3] = fmaf(av, b.w, acc[i][3]);

// ---------------- split fp32 -> hi/lo f16 planes ----------------
__global__ __launch_bounds__(256) void k_cvt(const float* __restrict__ in,
                                             _Float16* __restrict__ hi,
                                             _Float16* __restrict__ lo,
                                             int n) {
  const int i = (blockIdx.x * 256 + threadIdx.x) * 8;
  if (i >= n) return;
  const float4 a = *(const float4*)(in + i);
  const float4 b = *(const float4*)(in + i + 4);
  const float v[8] = {a.x, a.y, a.z, a.w, b.x, b.y, b.z, b.w};
  f16x8 h, l;
#pragma unroll
  for (int j = 0; j < 8; ++j) {
    const _Float16 hh = (_Float16)v[j];
    h[j] = hh;
    l[j] = (_Float16)(v[j] - (float)hh);
  }
  *(f16x8*)(hi + i) = h;
  *(f16x8*)(lo + i) = l;
}

// ---------------- f16x3 NT GEMM: D[m][n] = sum_k A[m,k]*B[n,k], K=LD=1024 ----
template <int EPI>
__global__ __launch_bounds__(256) void kgemm_f16x3(
    const _Float16* __restrict__ Ah, const _Float16* __restrict__ Al,
    const _Float16* __restrict__ Bh, const _Float16* __restrict__ Bl,
    float* __restrict__ out0, float* __restrict__ out1) {
  __shared__ _Float16 sm[16384];  // 32 KB: Ah|Al|Bh|Bl tiles, 128x32 packed
  _Float16* Ash = sm;
  _Float16* Asl = sm + 4096;
  _Float16* Bsh = sm + 8192;
  _Float16* Bsl = sm + 12288;

  const int tid = threadIdx.x;
  const int wid = tid >> 6, lane = tid & 63;
  const int wm = wid >> 1, wn = wid & 1;
  const int m0 = blockIdx.y * 128;
  const int n0 = blockIdx.x * 128;

  const int r0 = wid * 32;
  const int srow = lane >> 2;
  const int skq = (lane & 3) * 8;
  const _Float16* gAh = Ah + (size_t)(m0 + r0 + srow) * 1024 + skq;
  const _Float16* gAl = Al + (size_t)(m0 + r0 + srow) * 1024 + skq;
  const _Float16* gBh = Bh + (size_t)(n0 + r0 + srow) * 1024 + skq;
  const _Float16* gBl = Bl + (size_t)(n0 + r0 + srow) * 1024 + skq;
  _Float16* lAh = Ash + r0 * 32;
  _Float16* lAl = Asl + r0 * 32;
  _Float16* lBh = Bsh + r0 * 32;
  _Float16* lBl = Bsl + r0 * 32;

  const int fr = lane & 15;
  const int fk = (lane >> 4) * 8;

  f32x4 acc[4][4];
#pragma unroll
  for (int i = 0; i < 4; ++i)
#pragma unroll
    for (int j = 0; j < 4; ++j) acc[i][j] = (f32x4)(0.f);

  for (int k0 = 0; k0 < 1024; k0 += 32) {
    __syncthreads();
    gl_lds16(gAh + k0, lAh);
    gl_lds16(gAh + k0 + 16 * 1024, lAh + 512);
    gl_lds16(gAl + k0, lAl);
    gl_lds16(gAl + k0 + 16 * 1024, lAl + 512);
    gl_lds16(gBh + k0, lBh);
    gl_lds16(gBh + k0 + 16 * 1024, lBh + 512);
    gl_lds16(gBl + k0, lBl);
    gl_lds16(gBl + k0 + 16 * 1024, lBl + 512);
    __syncthreads();

    f16x8 ah[4], alo[4], bh[4], blo[4];
#pragma unroll
    for (int i = 0; i < 4; ++i) {
      const int ao = (wm * 64 + i * 16 + fr) * 32 + fk;
      const int bo = (wn * 64 + i * 16 + fr) * 32 + fk;
      ah[i]  = *(const f16x8*)(Ash + ao);
      alo[i] = *(const f16x8*)(Asl + ao);
      bh[i]  = *(const f16x8*)(Bsh + bo);
      blo[i] = *(const f16x8*)(Bsl + bo);
    }
#pragma unroll
    for (int i = 0; i < 4; ++i)
#pragma unroll
      for (int j = 0; j < 4; ++j) {
        acc[i][j] = __builtin_amdgcn_mfma_f32_16x16x32_f16(ah[i], bh[j],
                                                           acc[i][j], 0, 0, 0);
        acc[i][j] = __builtin_amdgcn_mfma_f32_16x16x32_f16(ah[i], blo[j],
                                                           acc[i][j], 0, 0, 0);
        acc[i][j] = __builtin_amdgcn_mfma_f32_16x16x32_f16(alo[i], bh[j],
                                                           acc[i][j], 0, 0, 0);
      }
  }

  const int lr4 = (lane >> 4) * 4, lc = lane & 15;
#pragma unroll
  for (int i = 0; i < 4; ++i) {
#pragma unroll
    for (int j = 0; j < 4; ++j) {
      const int ar = m0 + wm * 64 + i * 16 + lr4;
      const int bc = n0 + wn * 64 + j * 16 + lc;
#pragma unroll
      for (int r = 0; r < 4; ++r) {
        const float v = acc[i][j][r];
        if (EPI == 0) {
          out0[(size_t)(ar + r) * 1024 + bc] = v;
        } else {
          const int bb = bc >> 11, tt = bc & 2047;
          if (ar < 1024) {
            out0[((size_t)bb * 1024 + ar + r) * 2048 + tt] = v;
          } else {
            out1[((size_t)bb * 1024 + (ar + r - 1024)) * 2048 + tt] = v;
          }
        }
      }
    }
  }
}

// ---------------- conv: depthwise k=3, pad=1, along t ----------------
__global__ __launch_bounds__(256) void k_conv(
    const float* __restrict__ xcraw, const float* __restrict__ cw,
    const float* __restrict__ cb, float* __restrict__ xc) {
  const int idx = blockIdx.x * 256 + threadIdx.x;
  const int t0 = (idx & (SEQ / 4 - 1)) * 4;
  const int r = idx >> 9;  // b*DIM + d
  const int d = r & (DIM - 1);
  const float w0 = cw[d * 3 + 0], w1 = cw[d * 3 + 1], w2 = cw[d * 3 + 2];
  const float bias = cb[d];
  const float* in = xcraw + (size_t)r * SEQ;
  float o[4];
#pragma unroll
  for (int j = 0; j < 4; ++j) {
    const int t = t0 + j;
    const float xm = (t > 0) ? in[t - 1] : 0.f;
    const float x0 = in[t];
    const float xp = (t < SEQ - 1) ? in[t + 1] : 0.f;
    o[j] = fmaf(w0, xm, fmaf(w1, x0, fmaf(w2, xp, bias)));
  }
  *(float4*)(xc + (size_t)r * SEQ + t0) = make_float4(o[0], o[1], o[2], o[3]);
}

// ---------------- K2: x_proj split-K GEMM ----------------
__global__ __launch_bounds__(256) void k2_xproj_sk(
    const float* __restrict__ xc, const float* __restrict__ wp,
    float* __restrict__ part) {
  __shared__ float As[16][100];   // [kk][j], +4 pad
  __shared__ float Bs[16][132];   // [kk][t], +4 pad
  const int tid = threadIdx.x;
  const int tile = blockIdx.x;            // 0..31
  const int ks = blockIdx.y;              // 0..KSL-1
  const int b = tile >> 4;
  const int t0 = (tile & 15) * 128;
  const int kbase = ks * (DIM / KSL);     // 128-wide K slice
  const int tx = tid & 15, ty = tid >> 4;
  float acc[6][8] = {{0.f}};
  for (int k = 0; k < DIM / KSL; k += 16) {
    float a_reg[6];
#pragma unroll
    for (int i = 0; i < 6; ++i) {
      const int ii = tid + 256 * i;
      a_reg[i] = wp[(size_t)(ii >> 4) * DIM + kbase + k + (ii & 15)];
    }
    float4 b_reg[2];
#pragma unroll
    for (int r = 0; r < 2; ++r) {
      const int id2 = tid + 256 * r;
      const int krow = id2 >> 5, t4 = (id2 & 31) * 4;
      b_reg[r] = *(const float4*)(xc + ((size_t)b * DIM + kbase + k + krow) *
                                           SEQ + t0 + t4);
    }
    __syncthreads();
#pragma unroll
    for (int i = 0; i < 6; ++i) {
      const int ii = tid + 256 * i;
      As[ii & 15][ii >> 4] = a_reg[i];
    }
#pragma unroll
    for (int r = 0; r < 2; ++r) {
      const int id2 = tid + 256 * r;
      const int krow = id2 >> 5, t4 = (id2 & 31) * 4;
      *(float4*)&Bs[krow][t4] = b_reg[r];
    }
    __syncthreads();
#pragma unroll
    for (int kk = 0; kk < 16; ++kk) {
      const float4 bA = *(const float4*)&Bs[kk][tx * 4];
      const float4 bB = *(const float4*)&Bs[kk][64 + tx * 4];
#pragma unroll
      for (int i = 0; i < 6; ++i) {
        const float a = As[kk][ty + 16 * i];
        acc[i][0] = fmaf(a, bA.x, acc[i][0]);
        acc[i][1] = fmaf(a, bA.y, acc[i][1]);
        acc[i][2] = fmaf(a, bA.z, acc[i][2]);
        acc[i][3] = fmaf(a, bA.w, acc[i][3]);
        acc[i][4] = fmaf(a, bB.x, acc[i][4]);
        acc[i][5] = fmaf(a, bB.y, acc[i][5]);
        acc[i][6] = fmaf(a, bB.z, acc[i][6]);
        acc[i][7] = fmaf(a, bB.w, acc[i][7]);
      }
    }
    __syncthreads();
  }
#pragma unroll
  for (int i = 0; i < 6; ++i) {
    const int j = ty + 16 * i;
    const size_t o = ((size_t)(ks * BATCH + b) * 96 + j) * SEQ + t0;
    *(float4*)(part + o + tx * 4) =
        make_float4(acc[i][0], acc[i][1], acc[i][2], acc[i][3]);
    *(float4*)(part + o + 64 + tx * 4) =
        make_float4(acc[i][4], acc[i][5], acc[i][6], acc[i][7]);
  }
}

// ---------------- reduce split-K partials -> xdbl ----------------
__global__ __launch_bounds__(256) void k_red(const float* __restrict__ part,
                                             float* __restrict__ xdbl) {
  const size_t PL = (size_t)BATCH * 96 * SEQ;  // 393216
  const size_t i4 = ((size_t)blockIdx.x * 256 + threadIdx.x) * 4;
  float4 s = *(const float4*)(part + i4);
#pragma unroll
  for (int ks = 1; ks < KSL; ++ks) {
    const float4 v = *(const float4*)(part + ks * PL + i4);
    s.x += v.x; s.y += v.y; s.z += v.z; s.w += v.w;
  }
  *(float4*)(xdbl + i4) = s;
}

// ---------------- K3: dt_proj GEMM + softplus (fp32, small) ----------------
__global__ __launch_bounds__(256) void k3_dtproj(
    const float* __restrict__ xdbl, const float* __restrict__ dtw,
    const float* __restrict__ dtb, float* __restrict__ delta) {
  __shared__ float As[16][68];
  __shared__ float Bs[16][68];
  const int tid = threadIdx.x;
  const int b = blockIdx.z;
  const int d0 = blockIdx.y * 64;
  const int t0 = blockIdx.x * 64;
  const int tx = tid & 15, ty = tid >> 4;
  const int lrow = tid >> 2, lcol = (tid & 3) * 4;
  const int bk = tid >> 4, bt4 = (tid & 15) * 4;
  float acc[4][4] = {{0.f}};
  for (int k = 0; k < DTR; k += 16) {
    const float4 av =
        *(const float4*)(dtw + (size_t)(d0 + lrow) * DTR + k + lcol);
    const float4 bv =
        *(const float4*)(xdbl + ((size_t)b * 96 + k + bk) * SEQ + t0 + bt4);
    __syncthreads();
    As[lcol + 0][lrow] = av.x; As[lcol + 1][lrow] = av.y;
    As[lcol + 2][lrow] = av.z; As[lcol + 3][lrow] = av.w;
    Bs[bk][bt4 + 0] = bv.x; Bs[bk][bt4 + 1] = bv.y;
    Bs[bk][bt4 + 2] = bv.z; Bs[bk][bt4 + 3] = bv.w;
    __syncthreads();
#pragma unroll
    for (int kk = 0; kk < 16; ++kk) {
      const float4 a = *(const float4*)&As[kk][ty * 4];
      const float4 b = *(const float4*)&Bs[kk][tx * 4];
      FMA_ROW(0, a.x) FMA_ROW(1, a.y) FMA_ROW(2, a.z) FMA_ROW(3, a.w)
    }
  }
#pragma unroll
  for (int i = 0; i < 4; ++i) {
    const int d = d0 + ty * 4 + i;
    const float bias = dtb[d];
    float4 v;
    v.x = softplus_f(acc[i][0] + bias);
    v.y = softplus_f(acc[i][1] + bias);
    v.z = softplus_f(acc[i][2] + bias);
    v.w = softplus_f(acc[i][3] + bias);
    *(float4*)(delta + ((size_t)b * DIM + d) * SEQ + t0 + tx * 4) = v;
  }
}

// ---------------- fused scan: t-parallel Hillis-Steele + n-reduce + gate ----
// Block = one (b,d) row, 1024 threads = 16 waves, wave wv handles state n=wv.
// Per 256-t window: lane i holds t=4i..4i+3; (a,b) pairs composed locally
// (3 steps), 6-step __shfl_up inclusive scan of lane aggregates, exclusive
// prefix + window carry reconstruct all 256 states; y-partials (s*C, +u*D on
// wv==0) written to double-buffered LDS; threads<256 reduce over 16 n,
// apply gate *silu(z), store y (b,d,t). One barrier per window; reduce of
// window w overlaps compute of w+1 (alternate buffers).
__global__ __launch_bounds__(1024) void k_scan_fused(
    const float* __restrict__ delta, const float* __restrict__ u,
    const float* __restrict__ xdbl, const float* __restrict__ A_log,
    const float* __restrict__ Dp, const float* __restrict__ z,
    float* __restrict__ y) {
  __shared__ float red[2][NST][260];   // 33 KB
  const int tid = threadIdx.x;
  const int wv = tid >> 6;             // 0..15 == n
  const int lane = tid & 63;
  const int idx = blockIdx.x;          // b*DIM + d
  const int b = idx >> 10, d = idx & (DIM - 1);
  const float A = -expf(A_log[d * NST + wv]);
  const float Dprm = Dp[d];
  const float* drow = delta + (size_t)idx * SEQ;
  const float* urow = u + (size_t)idx * SEQ;
  const float* Brow = xdbl + ((size_t)b * 96 + DTR + wv) * SEQ;
  const float* Crow = xdbl + ((size_t)b * 96 + DTR + NST + wv) * SEQ;
  const float* zrow = z + (size_t)idx * SEQ;
  float* yrow = y + (size_t)idx * SEQ;
  float s_c = 0.f;                     // running state carry for (b,d,n)
  const int tl = lane * 4;

  float4 dl = *(const float4*)(drow + tl);
  float4 uu = *(const float4*)(urow + tl);
  float4 Bv = *(const float4*)(Brow + tl);
  float4 Cv = *(const float4*)(Crow + tl);

  for (int w = 0; w < SEQ / 256; ++w) {
    const int t0 = w * 256;
    const float dls[4] = {dl.x, dl.y, dl.z, dl.w};
    const float us[4]  = {uu.x, uu.y, uu.z, uu.w};
    const float Bb[4]  = {Bv.x, Bv.y, Bv.z, Bv.w};
    const float Cc[4]  = {Cv.x, Cv.y, Cv.z, Cv.w};
    if (w + 1 < SEQ / 256) {
      const int tn = t0 + 256 + tl;
      dl = *(const float4*)(drow + tn);
      uu = *(const float4*)(urow + tn);
      Bv = *(const float4*)(Brow + tn);
      Cv = *(const float4*)(Crow + tn);
    }
    // local (a,b) pairs + inclusive prefixes within the lane's 4 elems
    float p[4], q[4];
    {
      const float a0 = __expf(dls[0] * A), b0 = dls[0] * us[0] * Bb[0];
      p[0] = a0; q[0] = b0;
      const float a1 = __expf(dls[1] * A), b1 = dls[1] * us[1] * Bb[1];
      p[1] = a1 * p[0]; q[1] = fmaf(a1, q[0], b1);
      const float a2 = __expf(dls[2] * A), b2 = dls[2] * us[2] * Bb[2];
      p[2] = a2 * p[1]; q[2] = fmaf(a2, q[1], b2);
      const float a3 = __expf(dls[3] * A), b3 = dls[3] * us[3] * Bb[3];
      p[3] = a3 * p[2]; q[3] = fmaf(a3, q[2], b3);
    }
    // wave-wide inclusive scan of lane aggregates (compose op)
    float ia = p[3], ib = q[3];
#pragma unroll
    for (int sft = 1; sft < 64; sft <<= 1) {
      const float oa = __shfl_up(ia, sft, 64);
      const float ob = __shfl_up(ib, sft, 64);
      if (lane >= sft) { ib = fmaf(ia, ob, ib); ia = ia * oa; }
    }
    // window aggregate (lane 63) -> carry update
    const float Wa = __shfl(ia, 63, 64);
    const float Wb = __shfl(ib, 63, 64);
    // exclusive prefix for this lane
    float ea = __shfl_up(ia, 1, 64);
    float eb = __shfl_up(ib, 1, 64);
    if (lane == 0) { ea = 1.f; eb = 0.f; }
    const float S = fmaf(ea, s_c, eb);   // state entering lane's segment
    s_c = fmaf(Wa, s_c, Wb);
    // reconstruct per-element states, y-partials
    float4 yp;
    yp.x = fmaf(p[0], S, q[0]) * Cc[0];
    yp.y = fmaf(p[1], S, q[1]) * Cc[1];
    yp.z = fmaf(p[2], S, q[2]) * Cc[2];
    yp.w = fmaf(p[3], S, q[3]) * Cc[3];
    if (wv == 0) {
      yp.x = fmaf(us[0], Dprm, yp.x);
      yp.y = fmaf(us[1], Dprm, yp.y);
      yp.z = fmaf(us[2], Dprm, yp.z);
      yp.w = fmaf(us[3], Dprm, yp.w);
    }
    *(float4*)&red[w & 1][wv][tl] = yp;
    __syncthreads();
    if (tid < 256) {
      float sum = 0.f;
#pragma unroll
      for (int nn = 0; nn < NST; ++nn) sum += red[w & 1][nn][tid];
      const float zz = zrow[t0 + tid];
      yrow[t0 + tid] = sum * silu_f(zz);
    }
  }
}

// ---------------- transpose + split: y(b,d,t) -> gh/gl (b,t,d) f16 ----------
__global__ __launch_bounds__(256) void k_gt(
    const float* __restrict__ y, _Float16* __restrict__ gh,
    _Float16* __restrict__ gl) {
  __shared__ _Float16 th[64][68];  // [d_local][t_local]
  __shared__ _Float16 tl[64][68];
  const int ti = threadIdx.x;
  const int t0 = blockIdx.x * 64;
  const int d0 = blockIdx.y * 64;
  const int b = blockIdx.z;
  const int c4 = (ti & 15) * 4;
#pragma unroll
  for (int rr = 0; rr < 4; ++rr) {
    const int dl_ = (ti >> 4) + 16 * rr;
    const size_t base = ((size_t)b * DIM + d0 + dl_) * SEQ + t0 + c4;
    const float4 yv = *(const float4*)(y + base);
    const float gy[4] = {yv.x, yv.y, yv.z, yv.w};
#pragma unroll
    for (int k = 0; k < 4; ++k) {
      const _Float16 h = (_Float16)gy[k];
      th[dl_][c4 + k] = h;
      tl[dl_][c4 + k] = (_Float16)(gy[k] - (float)h);
    }
  }
  __syncthreads();
#pragma unroll
  for (int rr = 0; rr < 2; ++rr) {
    const int chunk = ti + 256 * rr;
    const int tloc = chunk >> 3;
    const int dchunk = (chunk & 7) * 8;
    f16x8 hv, lv;
#pragma unroll
    for (int j = 0; j < 8; ++j) {
      hv[j] = th[dchunk + j][tloc];
      lv[j] = tl[dchunk + j][tloc];
    }
    const size_t o = ((size_t)b * SEQ + t0 + tloc) * DIM + d0 + dchunk;
    *(f16x8*)(gh + o) = hv;
    *(f16x8*)(gl + o) = lv;
  }
}

extern "C" void kernel_launch(void* const* d_in, const int* in_sizes, int n_in,
                              void* d_out, int out_size, void* d_ws,
                              size_t ws_size, hipStream_t stream) {
  const float* x          = (const float*)d_in[0];
  const float* in_proj_w  = (const float*)d_in[1];
  const float* conv_w     = (const float*)d_in[2];
  const float* conv_b     = (const float*)d_in[3];
  const float* A_log      = (const float*)d_in[4];
  const float* D_param    = (const float*)d_in[5];
  const float* x_proj_w   = (const float*)d_in[6];
  const float* dt_proj_w  = (const float*)d_in[7];
  const float* dt_proj_b  = (const float*)d_in[8];
  const float* out_proj_w = (const float*)d_in[9];
  float* out = (float*)d_out;
  float* ws = (float*)d_ws;

  const size_t PLANE = (size_t)BATCH * SEQ * DIM;  // 4M floats (16 MB)
  float* xcraw = ws;               // plane0: xcraw -> delta -> gh/gl
  float* delta = ws;
  _Float16* gh = (_Float16*)ws;
  _Float16* gl = (_Float16*)ws + PLANE;
  float* xc    = ws + PLANE;       // (b,d,t) post-conv
  float* zbuf  = ws + 2 * PLANE;   // (b,dz,t) channel-major
  _Float16* xh = (_Float16*)(ws + 3 * PLANE);  // plane3: xh/xl -> part -> ybuf
  _Float16* xl = xh + PLANE;
  float* part  = ws + 3 * PLANE;
  float* ybuf  = ws + 3 * PLANE;
  float* xdbl  = ws + 4 * PLANE;   // (b,96,t) 393216 floats
  _Float16* wih = (_Float16*)(ws + 4 * PLANE + 1572864);
  _Float16* wil = wih + (size_t)2 * DIM * DIM;
  _Float16* woh = wil + (size_t)2 * DIM * DIM;
  _Float16* wol = woh + (size_t)DIM * DIM;

  k_cvt<<<dim3(2048), 256, 0, stream>>>(x, xh, xl, BATCH * SEQ * DIM);
  k_cvt<<<dim3(1024), 256, 0, stream>>>(in_proj_w, wih, wil, 2 * DIM * DIM);
  k_cvt<<<dim3(512), 256, 0, stream>>>(out_proj_w, woh, wol, DIM * DIM);

  kgemm_f16x3<1><<<dim3(32, 16), 256, 0, stream>>>(wih, wil, xh, xl,
                                                   xcraw, zbuf);
  k_conv<<<dim3((BATCH * DIM * SEQ / 4) / 256), 256, 0, stream>>>(
      xcraw, conv_w, conv_b, xc);
  k2_xproj_sk<<<dim3(32, KSL), 256, 0, stream>>>(xc, x_proj_w, part);
  k_red<<<dim3(384), 256, 0, stream>>>(part, xdbl);
  k3_dtproj<<<dim3(SEQ / 64, DIM / 64, BATCH), 256, 0, stream>>>(
      xdbl, dt_proj_w, dt_proj_b, delta);
  k_scan_fused<<<dim3(BATCH * DIM), 1024, 0, stream>>>(
      delta, xc, xdbl, A_log, D_param, zbuf, ybuf);
  k_gt<<<dim3(SEQ / 64, DIM / 64, BATCH), 256, 0, stream>>>(ybuf, gh, gl);
  kgemm_f16x3<0><<<dim3(8, 32), 256, 0, stream>>>(gh, gl, woh, wol,
                                                  out, nullptr);
}